// Round 14
// baseline (1172.189 us; speedup 1.0000x reference)
//
#include <hip/hip_runtime.h>
#include <math.h>

#define TS_ 19   // T-1 decode steps

typedef float f32x4 __attribute__((ext_vector_type(4)));
typedef short s16x8 __attribute__((ext_vector_type(8)));
typedef unsigned short us;
typedef unsigned char uc;

__device__ __forceinline__ float sigmoidf_(float x) { return 1.f / (1.f + __expf(-x)); }

__device__ __forceinline__ float fast_tanh(float x) {
    float ax = fabsf(x);
    float e = __expf(-2.f * ax);
    float r = (1.f - e) * __builtin_amdgcn_rcpf(1.f + e);
    return copysignf(r, x);
}

__device__ __forceinline__ us f2b(float x) {
    union { float f; unsigned u; } v; v.f = x;
    unsigned r = v.u + 0x7fffu + ((v.u >> 16) & 1u);
    return (us)(r >> 16);
}
__device__ __forceinline__ float b2f(us u) {
    union { unsigned u; float f; } v; v.u = ((unsigned)u) << 16; return v.f;
}
__device__ __forceinline__ uc f2e4m3(float x) {
    return (uc)(__builtin_amdgcn_cvt_pk_fp8_f32(x, 0.f, 0, false) & 0xff);
}

#define MFMA(a, b, c) __builtin_amdgcn_mfma_f32_16x16x32_bf16((a), (b), (c), 0, 0, 0)
#define MFMA8(a, b, c) __builtin_amdgcn_mfma_f32_16x16x32_fp8_fp8((a), (b), (c), 0, 0, 0)

__device__ __forceinline__ f32x4 zero4() { return (f32x4){0.f, 0.f, 0.f, 0.f}; }

__device__ __forceinline__ f32x4 wg16(const us* ap, const us* bp, int nk, f32x4 acc) {
#pragma unroll 4
    for (int k = 0; k < nk; k += 32)
        acc = MFMA(*(const s16x8*)(ap + k), *(const s16x8*)(bp + k), acc);
    return acc;
}

// async global -> LDS, 16B per lane; dest = wave-uniform base + lane*16
__device__ __forceinline__ void gload_lds16(const void* g, void* l) {
    __builtin_amdgcn_global_load_lds(
        (const __attribute__((address_space(1))) unsigned int*)g,
        (__attribute__((address_space(3))) unsigned int*)l, 16, 0, 0);
}

// ---------------- prep kernels ----------------
__global__ __launch_bounds__(256) void k_cvt(const float* __restrict__ in,
                                             us* __restrict__ out, long n) {
    long i = ((long)blockIdx.x * 256 + threadIdx.x) * 4;
    long stride = (long)gridDim.x * 1024;
    for (; i < n; i += stride) {
        float4 v = *(const float4*)(in + i);
        ushort4 o = { f2b(v.x), f2b(v.y), f2b(v.z), f2b(v.w) };
        *(ushort4*)(out + i) = o;
    }
}

__global__ __launch_bounds__(256) void k_cvt8(const float* __restrict__ in,
                                              uc* __restrict__ out, long n) {
    long i = ((long)blockIdx.x * 256 + threadIdx.x) * 8;
    long stride = (long)gridDim.x * 2048;
    for (; i < n; i += stride) {
        float4 v0 = *(const float4*)(in + i);
        float4 v1 = *(const float4*)(in + i + 4);
        int lo = __builtin_amdgcn_cvt_pk_fp8_f32(v0.x, v0.y, 0, false);
        lo = __builtin_amdgcn_cvt_pk_fp8_f32(v0.z, v0.w, lo, true);
        int hi = __builtin_amdgcn_cvt_pk_fp8_f32(v1.x, v1.y, 0, false);
        hi = __builtin_amdgcn_cvt_pk_fp8_f32(v1.z, v1.w, hi, true);
        int2 o = { lo, hi };
        *(int2*)(out + i) = o;
    }
}

__global__ void k_tcvt(const float* __restrict__ in, us* __restrict__ out) {
    __shared__ float tile[32][33];
    int bx = blockIdx.x * 32, by = blockIdx.y * 32;
    int x = threadIdx.x, y0 = threadIdx.y;
    for (int yy = y0; yy < 32; yy += 8) tile[yy][x] = in[(by + yy) * 1024 + bx + x];
    __syncthreads();
    for (int yy = y0; yy < 32; yy += 8) out[(bx + yy) * 1024 + by + x] = f2b(tile[x][yy]);
}

__global__ __launch_bounds__(256) void k_yemb(const int* __restrict__ y,
                                              const float* __restrict__ embW,
                                              us* __restrict__ xc) {
    int t = blockIdx.x >> 6, b = blockIdx.x & 63;
    int row = y[t * 64 + b];
    const float* src = embW + (long)row * 512;
    us* dst = xc + (long)(t * 64 + b) * 2560;
    for (int e = threadIdx.x; e < 512; e += 256) dst[e] = f2b(src[e]);
}

// packed gate weights: rows 0..2047 r/z (K=2560 = Wih|Whh); 2048..3071 i_n (K=1536);
// 3072..4095 h_n (K=1024)
__global__ __launch_bounds__(256) void k_prepw(const float* __restrict__ Wih,
                                               const float* __restrict__ Whh,
                                               us* __restrict__ Wg) {
    int n = blockIdx.x, tid = threadIdx.x;
    int cl = n >> 10;
    if (cl < 2) {
        long base = (long)n * 2560;
        const float* wi = Wih + (long)n * 1536;
        const float* wh = Whh + (long)n * 1024;
        for (int k = tid; k < 1536; k += 256) Wg[base + k] = f2b(wi[k]);
        for (int k = tid; k < 1024; k += 256) Wg[base + 1536 + k] = f2b(wh[k]);
    } else if (cl == 2) {
        long base = 5242880L + (long)(n - 2048) * 1536;
        const float* wi = Wih + (long)n * 1536;
        for (int k = tid; k < 1536; k += 256) Wg[base + k] = f2b(wi[k]);
    } else {
        long base = 6815744L + (long)(n - 3072) * 1024;
        const float* wh = Whh + (long)(n - 1024) * 1024;
        for (int k = tid; k < 1024; k += 256) Wg[base + k] = f2b(wh[k]);
    }
}

// ---------------- ctx_proj GEMM (m97 structure): 128x128 tile, BK=64 ----------
__global__ __launch_bounds__(256) void k_gemm(const us* __restrict__ A,
                                              const us* __restrict__ Bt,
                                              us* __restrict__ Cb) {
    __shared__ us As[8192], Bs[8192];   // 128 rows x 64 elems each
    int tid = threadIdx.x, lane = tid & 63, w = tid >> 6;
    int mr = lane & 15, kb = lane >> 4;
    int bm = blockIdx.x % 98, bn = blockIdx.x / 98;
    long m0 = (long)bm * 128;
    int n0 = bn * 128;
    int wr = w >> 1, wc = w & 1;
    int srow = w * 32 + (lane >> 3);
    int ib = (lane & 7) * 16;

    f32x4 acc[4][4];
#pragma unroll
    for (int i = 0; i < 4; i++)
#pragma unroll
        for (int j = 0; j < 4; j++) acc[i][j] = zero4();

    for (int kt = 0; kt < 16; ++kt) {
        int k0 = kt * 64;
        __syncthreads();
#pragma unroll
        for (int c = 0; c < 4; ++c) {
            int r = srow + c * 8;
            int sw = (ib ^ ((r & 7) << 4)) >> 1;   // element offset within row
            gload_lds16(A + (m0 + r) * 1024 + k0 + sw, &As[w * 2048 + c * 512]);
            gload_lds16(Bt + (long)(n0 + r) * 1024 + k0 + sw, &Bs[w * 2048 + c * 512]);
        }
        __syncthreads();
#pragma unroll
        for (int ks = 0; ks < 2; ++ks) {
            s16x8 af[4], bf[4];
#pragma unroll
            for (int mt = 0; mt < 4; ++mt) {
                int r = wr * 64 + mt * 16 + mr;
                af[mt] = *(const s16x8*)&As[(r * 128 + ((ks * 64 + kb * 16) ^ ((r & 7) << 4))) >> 1];
            }
#pragma unroll
            for (int nt = 0; nt < 4; ++nt) {
                int r = wc * 64 + nt * 16 + mr;
                bf[nt] = *(const s16x8*)&Bs[(r * 128 + ((ks * 64 + kb * 16) ^ ((r & 7) << 4))) >> 1];
            }
#pragma unroll
            for (int mt = 0; mt < 4; ++mt)
#pragma unroll
                for (int nt = 0; nt < 4; ++nt)
                    acc[mt][nt] = MFMA(af[mt], bf[nt], acc[mt][nt]);
        }
    }
#pragma unroll
    for (int mt = 0; mt < 4; ++mt)
#pragma unroll
        for (int nt = 0; nt < 4; ++nt)
#pragma unroll
            for (int j = 0; j < 4; ++j)
                Cb[(m0 + wr * 64 + mt * 16 + kb * 4 + j) * 1024 +
                   n0 + wc * 64 + nt * 16 + mr] = f2b(acc[mt][nt][j]);
}

// ---------------- hproj parts: hpp[kc][b][n] = (h_t @ attT)_Khalf ----------------
__global__ __launch_bounds__(256) void k_hproj(const us* __restrict__ hcur,
                                               const us* __restrict__ attbf,
                                               float* __restrict__ hpp) {
    int tid = threadIdx.x, lane = tid & 63, w = tid >> 6;
    int vn0 = (blockIdx.x >> 1) * 16, kc = blockIdx.x & 1;
    int m0 = w * 16, mr = lane & 15, kb = lane >> 4;
    const us* ap = hcur + (long)(m0 + mr) * 1024 + kc * 512 + kb * 8;
    const us* bp = attbf + (long)(vn0 + mr) * 1024 + kc * 512 + kb * 8;
    f32x4 acc = wg16(ap, bp, 512, zero4());
#pragma unroll
    for (int j = 0; j < 4; ++j)
        hpp[(long)kc * 65536 + (long)(m0 + kb * 4 + j) * 1024 + vn0 + mr] = acc[j];
}

// ---------------- fused attention: scores + softmax + z-half, 2 blocks per b ---
__global__ __launch_bounds__(1024) void k_att2(const us* __restrict__ cpb,
                                               const float* __restrict__ hpp,
                                               const float* __restrict__ mlp,
                                               const us* __restrict__ ctxbf,
                                               us* __restrict__ xc, int t) {
    __shared__ float hp[1024];
    __shared__ float ml[1024];
    __shared__ float scs[200];
    __shared__ float als[200];
    __shared__ float zp[3][512];
    int tid = threadIdx.x;
    int b = blockIdx.x >> 1, chalf = blockIdx.x & 1;

    hp[tid] = hpp[(long)b * 1024 + tid] + hpp[65536 + (long)b * 1024 + tid];
    ml[tid] = mlp[tid];
    __syncthreads();

    // scores: wave wv handles s = wv, wv+16, ... (all 196 per block)
    {
        int wv = tid >> 6, lane = tid & 63;
        for (int s = wv; s < 196; s += 16) {
            const us* cp = cpb + (long)(s * 64 + b) * 1024 + lane * 16;
            s16x8 c0 = *(const s16x8*)cp;
            s16x8 c1 = *(const s16x8*)(cp + 8);
            int e0 = lane * 16;
            float acc = 0.f;
#pragma unroll
            for (int j = 0; j < 8; ++j)
                acc += fast_tanh(b2f((us)c0[j]) + hp[e0 + j]) * ml[e0 + j];
#pragma unroll
            for (int j = 0; j < 8; ++j)
                acc += fast_tanh(b2f((us)c1[j]) + hp[e0 + 8 + j]) * ml[e0 + 8 + j];
#pragma unroll
            for (int off = 32; off; off >>= 1) acc += __shfl_xor(acc, off, 64);
            if (lane == 0) scs[s] = acc;
        }
    }
    __syncthreads();

    // softmax (wave 0)
    if (tid < 64) {
        int lane = tid;
        float v0 = scs[lane], v1 = scs[lane + 64], v2 = scs[lane + 128];
        float v3 = (lane < 4) ? scs[192 + lane] : -1e30f;
        float m = fmaxf(fmaxf(v0, v1), fmaxf(v2, v3));
#pragma unroll
        for (int off = 32; off; off >>= 1) m = fmaxf(m, __shfl_xor(m, off, 64));
        float pI = __expf(v0 - m) + __expf(v1 - m) + __expf(v2 - m);
        if (lane < 4) pI += __expf(v3 - m);
#pragma unroll
        for (int off = 32; off; off >>= 1) pI += __shfl_xor(pI, off, 64);
        float inv = 1.f / pI;
        als[lane] = __expf(v0 - m) * inv;
        als[lane + 64] = __expf(v1 - m) * inv;
        als[lane + 128] = __expf(v2 - m) * inv;
        if (lane < 4) als[192 + lane] = __expf(v3 - m) * inv;
    }
    __syncthreads();

    // z for this block's c-half: 256 c-pairs x 4 s-quarters, LDS combine
    {
        int cp2 = tid & 255, sq = tid >> 8;
        int c = chalf * 512 + cp2 * 2;
        const us* cptr = ctxbf + (long)b * 1024 + c;
        float a0 = 0.f, a1 = 0.f;
        int sb = sq * 49;
#pragma unroll 7
        for (int s = sb; s < sb + 49; ++s) {
            float al = als[s];
            ushort2 v = *(const ushort2*)(cptr + (long)s * 65536);
            a0 += al * b2f(v.x);
            a1 += al * b2f(v.y);
        }
        if (sq) { zp[sq - 1][cp2 * 2] = a0; zp[sq - 1][cp2 * 2 + 1] = a1; }
        __syncthreads();
        if (sq == 0) {
            a0 += zp[0][cp2 * 2] + zp[1][cp2 * 2] + zp[2][cp2 * 2];
            a1 += zp[0][cp2 * 2 + 1] + zp[1][cp2 * 2 + 1] + zp[2][cp2 * 2 + 1];
            ushort2 o = { f2b(a0), f2b(a1) };
            *(ushort2*)(xc + (long)(t * 64 + b) * 2560 + 512 + c) = o;
        }
    }
}

// ---------------- fused GRU: all 4 gates + update; XCD-co-located j-tiles -----
__global__ __launch_bounds__(512) void k_gruh2(us* __restrict__ xc,
                                               const us* __restrict__ Wg,
                                               const float* __restrict__ bih,
                                               const float* __restrict__ bhh,
                                               float* __restrict__ hf32,
                                               us* __restrict__ ht_all, int t) {
    __shared__ float lg[2048];   // [g*2+kh][m16][j16]
    int tid = threadIdx.x, lane = tid & 63, w = tid >> 6;
    int mr = lane & 15, kb = lane >> 4;
    int g = w >> 1, kh = w & 1;
    // XCD co-location: the 4 m-subtiles of a j-tile land on one XCD (bid&7)
    int xcd = blockIdx.x & 7, idx = blockIdx.x >> 3;
    int jt = xcd * 8 + (idx >> 2), mq = idx & 3;
    int m0 = mq * 16, j0 = jt * 16;
    const us* xr = xc + (long)t * 163840 + (long)(m0 + mr) * 2560;

    f32x4 acc = zero4();
    if (g == 0) {
        acc = wg16(xr + kh * 1280 + kb * 8,
                   Wg + (long)(j0 + mr) * 2560 + kh * 1280 + kb * 8, 1280, acc);
    } else if (g == 1) {
        acc = wg16(xr + kh * 1280 + kb * 8,
                   Wg + (long)(1024 + j0 + mr) * 2560 + kh * 1280 + kb * 8, 1280, acc);
    } else if (g == 2) {
        acc = wg16(xr + kh * 768 + kb * 8,
                   Wg + 5242880L + (long)(j0 + mr) * 1536 + kh * 768 + kb * 8, 768, acc);
    } else {
        acc = wg16(xr + 1536 + kh * 512 + kb * 8,
                   Wg + 6815744L + (long)(j0 + mr) * 1024 + kh * 512 + kb * 8, 512, acc);
    }
#pragma unroll
    for (int j = 0; j < 4; ++j)
        lg[(g * 2 + kh) * 256 + (kb * 4 + j) * 16 + mr] = acc[j];
    __syncthreads();

    if (tid < 256) {
        int ml = tid >> 4, jj = tid & 15;
        int b = m0 + ml, j = j0 + jj;
        float gr = lg[0 * 256 + ml * 16 + jj] + lg[1 * 256 + ml * 16 + jj];
        float gz = lg[2 * 256 + ml * 16 + jj] + lg[3 * 256 + ml * 16 + jj];
        float gi = lg[4 * 256 + ml * 16 + jj] + lg[5 * 256 + ml * 16 + jj];
        float gh = lg[6 * 256 + ml * 16 + jj] + lg[7 * 256 + ml * 16 + jj];
        float r  = sigmoidf_(gr + bih[j] + bhh[j]);
        float zz = sigmoidf_(gz + bih[1024 + j] + bhh[1024 + j]);
        float n  = fast_tanh(gi + bih[2048 + j] + r * (gh + bhh[2048 + j]));
        float h = (1.f - zz) * n + zz * hf32[b * 1024 + j];
        hf32[b * 1024 + j] = h;
        us hb = f2b(h);
        ht_all[(long)((t + 1) * 64 + b) * 1024 + j] = hb;
        if (t < TS_ - 1) xc[(long)((t + 1) * 64 + b) * 2560 + 1536 + j] = hb;
    }
}

// ---------------- batched output head: 152 blocks (19 m x 8 n of 64) ----------
__global__ __launch_bounds__(256) void k_outb(const us* __restrict__ ht_all,
                                              const us* __restrict__ xc,
                                              const us* __restrict__ h2obf,
                                              const float* __restrict__ h2ob,
                                              const us* __restrict__ octxbf,
                                              const float* __restrict__ octxb,
                                              us* __restrict__ obf_all,
                                              uc* __restrict__ obf8) {
    int tid = threadIdx.x, lane = tid & 63, w = tid >> 6;
    int mr = lane & 15, kb = lane >> 4;
    int m0 = blockIdx.x * 64;
    int n0 = blockIdx.y * 64;
    int e = n0 + w * 16 + mr;
    const us* bb1 = h2obf + (long)e * 1024 + kb * 8;
    const us* bb2 = octxbf + (long)e * 1024 + kb * 8;
    const us* ab1 = ht_all + (long)(64 + m0 + mr) * 1024 + kb * 8;
    const us* ab2 = xc + (long)(m0 + mr) * 2560 + 512 + kb * 8;

    f32x4 a1[4], a2[4];
#pragma unroll
    for (int i = 0; i < 4; i++) { a1[i] = zero4(); a2[i] = zero4(); }

#pragma unroll 2
    for (int k0 = 0; k0 < 1024; k0 += 32) {
        s16x8 b1 = *(const s16x8*)(bb1 + k0);
        s16x8 b2 = *(const s16x8*)(bb2 + k0);
#pragma unroll
        for (int mt = 0; mt < 4; ++mt) {
            a1[mt] = MFMA(*(const s16x8*)(ab1 + mt * 16384 + k0), b1, a1[mt]);
            a2[mt] = MFMA(*(const s16x8*)(ab2 + mt * 40960 + k0), b2, a2[mt]);
        }
    }
    float b1v = h2ob[e], b2v = octxb[e];
#pragma unroll
    for (int mt = 0; mt < 4; ++mt)
#pragma unroll
        for (int j = 0; j < 4; ++j) {
            long row = m0 + mt * 16 + kb * 4 + j;
            float ye = b2f(xc[row * 2560 + e]);
            float val = fast_tanh(fast_tanh(a1[mt][j] + b1v) + ye + a2[mt][j] + b2v);
            obf_all[(row << 9) + e] = f2b(val);
            obf8[(row << 9) + e] = f2e4m3(val);
        }
}

// ---------------- vocab GEMM (fp8, m97 structure) + partial LSE ----------------
__global__ __launch_bounds__(256) void k_vocab8(const uc* __restrict__ obf8,
                                                const uc* __restrict__ o2p8,
                                                const float* __restrict__ o2pb,
                                                float* __restrict__ pm,
                                                float* __restrict__ ps) {
    __shared__ uc As[8192], Bs[8192];   // 128 rows x 64 B each
    int tid = threadIdx.x, lane = tid & 63, w = tid >> 6;
    int mr = lane & 15, kb = lane >> 4;
    int xq = blockIdx.x & 7, idx = blockIdx.x >> 3;
    int nb = xq * 32 + idx / 10, mb = idx % 10;
    int m0 = mb * 128, n0 = nb * 128;
    int wr = w >> 1, wc = w & 1;
    int srow = w * 32 + (lane >> 2);
    int ib = (lane & 3) * 16;

    f32x4 acc[4][4];
#pragma unroll
    for (int i = 0; i < 4; i++)
#pragma unroll
        for (int j = 0; j < 4; j++) acc[i][j] = zero4();

    for (int kt = 0; kt < 8; ++kt) {
        int k0 = kt * 64;
        __syncthreads();
#pragma unroll
        for (int c = 0; c < 2; ++c) {
            int r = srow + c * 16;
            int sw = ib ^ ((r & 6) << 3);
            gload_lds16(obf8 + (long)(m0 + r) * 512 + k0 + sw, &As[w * 2048 + c * 1024]);
            gload_lds16(o2p8 + (long)(n0 + r) * 512 + k0 + sw, &Bs[w * 2048 + c * 1024]);
        }
        __syncthreads();
#pragma unroll
        for (int ks = 0; ks < 2; ++ks) {
            long af[4], bf[4];
#pragma unroll
            for (int mt = 0; mt < 4; ++mt) {
                int r = wr * 64 + mt * 16 + mr;
                af[mt] = *(const long*)&As[r * 64 + ((ks * 32 + kb * 8) ^ ((r & 6) << 3))];
            }
#pragma unroll
            for (int nt = 0; nt < 4; ++nt) {
                int r = wc * 64 + nt * 16 + mr;
                bf[nt] = *(const long*)&Bs[r * 64 + ((ks * 32 + kb * 8) ^ ((r & 6) << 3))];
            }
#pragma unroll
            for (int mt = 0; mt < 4; ++mt)
#pragma unroll
                for (int nt = 0; nt < 4; ++nt)
                    acc[mt][nt] = MFMA8(af[mt], bf[nt], acc[mt][nt]);
        }
    }

    int n0w = n0 + wc * 64;
    float bv[4];
#pragma unroll
    for (int nt = 0; nt < 4; ++nt) {
        int vn = n0w + nt * 16 + mr;
        bv[nt] = (vn < 32000) ? o2pb[vn] : -1e30f;
    }
#pragma unroll
    for (int mt = 0; mt < 4; ++mt)
#pragma unroll
        for (int j = 0; j < 4; ++j) {
            float x0 = acc[mt][0][j] + bv[0];
            float x1 = acc[mt][1][j] + bv[1];
            float x2 = acc[mt][2][j] + bv[2];
            float x3 = acc[mt][3][j] + bv[3];
            float m = fmaxf(fmaxf(x0, x1), fmaxf(x2, x3));
            float s = __expf(x0 - m) + __expf(x1 - m) + __expf(x2 - m) + __expf(x3 - m);
#pragma unroll
            for (int off = 1; off <= 8; off <<= 1) {
                float mo = __shfl_xor(m, off, 64), so = __shfl_xor(s, off, 64);
                float nm = fmaxf(m, mo);
                s = s * __expf(m - nm) + so * __expf(mo - nm);
                m = nm;
            }
            if (mr == 0) {
                int row = m0 + wr * 64 + mt * 16 + kb * 4 + j;
                pm[(long)(nb * 2 + wc) * 1280 + row] = m;
                ps[(long)(nb * 2 + wc) * 1280 + row] = s;
            }
        }
}

// ---------------- final LSE reduce + NLL accumulate ----------------
__global__ __launch_bounds__(64) void k_lseb(const float* __restrict__ pm,
                                             const float* __restrict__ ps,
                                             const us* __restrict__ obf_all,
                                             const float* __restrict__ o2pW,
                                             const float* __restrict__ o2pb,
                                             const int* __restrict__ y,
                                             float* __restrict__ out) {
    int r = blockIdx.x, lane = threadIdx.x;
    int t = r >> 6, b = r & 63;
    int tgt = y[(t + 1) * 64 + b];
    float m = -1e30f, s = 0.f;
    for (int p = lane; p < 512; p += 64) {
        float mi = pm[(long)p * 1280 + r], si = ps[(long)p * 1280 + r];
        float nm = fmaxf(m, mi);
        s = s * __expf(m - nm) + si * __expf(mi - nm);
        m = nm;
    }
#pragma unroll
    for (int off = 32; off; off >>= 1) {
        float mo = __shfl_xor(m, off, 64), so = __shfl_xor(s, off, 64);
        float nm = fmaxf(m, mo);
        s = s * __expf(m - nm) + so * __expf(mo - nm);
        m = nm;
    }
    float d = 0.f;
    const float* wr = o2pW + (long)tgt * 512;
#pragma unroll
    for (int k = 0; k < 8; ++k)
        d += b2f(obf_all[(long)r * 512 + lane + k * 64]) * wr[lane + k * 64];
#pragma unroll
    for (int off = 32; off; off >>= 1) d += __shfl_xor(d, off, 64);
    if (lane == 0 && tgt != 0)
        atomicAdd(out, (m + __logf(s)) - (d + o2pb[tgt]));
}

extern "C" void kernel_launch(void* const* d_in, const int* in_sizes, int n_in,
                              void* d_out, int out_size, void* d_ws, size_t ws_size,
                              hipStream_t stream) {
    const float* ctx     = (const float*)d_in[0];
    const int*   y       = (const int*)d_in[1];
    const float* embW    = (const float*)d_in[2];
    const float* att_c2c = (const float*)d_in[3];
    const float* att_h2c = (const float*)d_in[4];
    const float* mlp     = (const float*)d_in[5];
    const float* Wih     = (const float*)d_in[6];
    const float* bih     = (const float*)d_in[7];
    const float* Whh     = (const float*)d_in[8];
    const float* bhh     = (const float*)d_in[9];
    const float* h2oW    = (const float*)d_in[10];
    const float* h2ob    = (const float*)d_in[11];
    const float* octxW   = (const float*)d_in[12];
    const float* octxb   = (const float*)d_in[13];
    const float* o2pW    = (const float*)d_in[14];
    const float* o2pb    = (const float*)d_in[15];
    float* out = (float*)d_out;

    char* base = (char*)d_ws;
    us* ctxbf   = (us*)base; base += 25690112L;   // [s][b][c] bf16 (= GEMM A)
    us* cpbf    = (us*)base; base += 25690112L;   // [12544][1024]; pm/ps alias after loop
    us* c2cT    = (us*)base; base += 2097152L;
    us* attbf   = (us*)base; base += 2097152L;
    us* Wg      = (us*)base; base += 15728640L;
    us* h2obf   = (us*)base; base += 1048576L;
    us* octxbf  = (us*)base; base += 1048576L;
    uc* o2p8    = (uc*)base; base += 16777216L;   // [32768][512] fp8, rows 32000+ zero
    us* xc      = (us*)base; base += 6225920L;    // [19][64][2560]
    us* ht_all  = (us*)base; base += 2621440L;    // [20*64][1024], rows 0..63 = h0 = 0
    us* obf_all = (us*)base; base += 1310720L;    // [1280][512] bf16, rows 1216+ pad
    uc* obf8    = (uc*)base; base += 655360L;     // [1280][512] fp8
    float* hf32   = (float*)base; base += 262144L;  // [64][1024]
    float* hpp    = (float*)base; base += 524288L;  // [2][64][1024]
    float* pm   = (float*)cpbf;                   // [512][1280] aliases cpbf (dead by then)
    float* ps   = pm + 655360L;

    (void)hipMemsetAsync(d_out, 0, sizeof(float), stream);
    (void)hipMemsetAsync(hf32, 0, 262144, stream);
    (void)hipMemsetAsync(ht_all, 0, 131072, stream);                 // h0 rows
    (void)hipMemsetAsync(obf_all + 1216L * 512, 0, 65536, stream);   // bf16 pad rows
    (void)hipMemsetAsync(obf8 + 1216L * 512, 0, 32768, stream);      // fp8 pad rows
    (void)hipMemsetAsync(o2p8 + 16384000L, 0, 393216, stream);       // weight pad rows
    (void)hipMemsetAsync(xc, 0, 6225920, stream);

    // prep
    k_yemb<<<TS_ * 64, 256, 0, stream>>>(y, embW, xc);
    k_tcvt<<<dim3(32, 32), dim3(32, 8), 0, stream>>>(att_c2c, c2cT);
    k_tcvt<<<dim3(32, 32), dim3(32, 8), 0, stream>>>(att_h2c, attbf);
    k_cvt<<<2048, 256, 0, stream>>>(ctx, ctxbf, 12845056L);
    k_cvt<<<512, 256, 0, stream>>>(h2oW, h2obf, 524288L);
    k_cvt<<<512, 256, 0, stream>>>(octxW, octxbf, 524288L);
    k_cvt8<<<2048, 256, 0, stream>>>(o2pW, o2p8, 16384000L);
    k_prepw<<<4096, 256, 0, stream>>>(Wih, Whh, Wg);
    k_gemm<<<784, 256, 0, stream>>>(ctxbf, c2cT, cpbf);

    // sequential recurrence: 3 kernels per step
    for (int t = 0; t < TS_; t++) {
        k_hproj<<<128, 256, 0, stream>>>(ht_all + (long)t * 65536, attbf, hpp);
        k_att2<<<128, 1024, 0, stream>>>(cpbf, hpp, mlp, ctxbf, xc, t);
        k_gruh2<<<256, 512, 0, stream>>>(xc, Wg, bih, bhh, hf32, ht_all, t);
    }

    // deferred output head, batched over all steps
    k_outb<<<dim3(19, 8), 256, 0, stream>>>(ht_all, xc, h2obf, h2ob, octxbf, octxb,
                                            obf_all, obf8);
    k_vocab8<<<2560, 256, 0, stream>>>(obf8, o2p8, o2pb, pm, ps);
    k_lseb<<<1216, 64, 0, stream>>>(pm, ps, obf_all, o2pW, o2pb, y, out);
}

// Round 15
// 982.750 us; speedup vs baseline: 1.1928x; 1.1928x over previous
//
#include <hip/hip_runtime.h>
#include <math.h>

#define TS_ 19   // T-1 decode steps

typedef float f32x4 __attribute__((ext_vector_type(4)));
typedef short s16x8 __attribute__((ext_vector_type(8)));
typedef unsigned short us;
typedef unsigned char uc;

__device__ __forceinline__ float sigmoidf_(float x) { return 1.f / (1.f + __expf(-x)); }

__device__ __forceinline__ float fast_tanh(float x) {
    float ax = fabsf(x);
    float e = __expf(-2.f * ax);
    float r = (1.f - e) * __builtin_amdgcn_rcpf(1.f + e);
    return copysignf(r, x);
}

__device__ __forceinline__ us f2b(float x) {
    union { float f; unsigned u; } v; v.f = x;
    unsigned r = v.u + 0x7fffu + ((v.u >> 16) & 1u);
    return (us)(r >> 16);
}
__device__ __forceinline__ float b2f(us u) {
    union { unsigned u; float f; } v; v.u = ((unsigned)u) << 16; return v.f;
}
__device__ __forceinline__ uc f2e4m3(float x) {
    return (uc)(__builtin_amdgcn_cvt_pk_fp8_f32(x, 0.f, 0, false) & 0xff);
}

#define MFMA(a, b, c) __builtin_amdgcn_mfma_f32_16x16x32_bf16((a), (b), (c), 0, 0, 0)
#define MFMA8(a, b, c) __builtin_amdgcn_mfma_f32_16x16x32_fp8_fp8((a), (b), (c), 0, 0, 0)

__device__ __forceinline__ f32x4 zero4() { return (f32x4){0.f, 0.f, 0.f, 0.f}; }

__device__ __forceinline__ f32x4 wg16(const us* ap, const us* bp, int nk, f32x4 acc) {
#pragma unroll 4
    for (int k = 0; k < nk; k += 32)
        acc = MFMA(*(const s16x8*)(ap + k), *(const s16x8*)(bp + k), acc);
    return acc;
}

// async global -> LDS, 16B per lane; dest = wave-uniform base + lane*16
__device__ __forceinline__ void gload_lds16(const void* g, void* l) {
    __builtin_amdgcn_global_load_lds(
        (const __attribute__((address_space(1))) unsigned int*)g,
        (__attribute__((address_space(3))) unsigned int*)l, 16, 0, 0);
}

// ---------------- mega prep: all conversions + weight packing + zero fills -----
__global__ __launch_bounds__(256) void k_prep(
    const float* __restrict__ ctx, us* __restrict__ ctxbf,
    const float* __restrict__ o2pW, uc* __restrict__ o2p8,
    const float* __restrict__ Wih, const float* __restrict__ Whh, us* __restrict__ Wg,
    const float* __restrict__ h2oW, us* __restrict__ h2obf,
    const float* __restrict__ octxW, us* __restrict__ octxbf,
    const float* __restrict__ att_c2c, us* __restrict__ c2cT,
    const float* __restrict__ att_h2c, us* __restrict__ attbf,
    const int* __restrict__ y, const float* __restrict__ embW, us* __restrict__ xc,
    float* __restrict__ hf32, us* __restrict__ ht_all,
    us* __restrict__ obf_all, uc* __restrict__ obf8, float* __restrict__ out) {
    __shared__ float tile[32][33];
    int bid = blockIdx.x, tid = threadIdx.x;
    const int4 z4 = {0, 0, 0, 0};

    if (bid < 1024) {                       // ctx -> bf16
        for (long i = ((long)bid * 256 + tid) * 4; i < 12845056L; i += 1048576L) {
            float4 v = *(const float4*)(ctx + i);
            ushort4 o = { f2b(v.x), f2b(v.y), f2b(v.z), f2b(v.w) };
            *(ushort4*)(ctxbf + i) = o;
        }
    } else if (bid < 1792) {                // o2pW -> fp8
        for (long i = ((long)(bid - 1024) * 256 + tid) * 8; i < 16384000L;
             i += 1572864L) {
            float4 v0 = *(const float4*)(o2pW + i);
            float4 v1 = *(const float4*)(o2pW + i + 4);
            int lo = __builtin_amdgcn_cvt_pk_fp8_f32(v0.x, v0.y, 0, false);
            lo = __builtin_amdgcn_cvt_pk_fp8_f32(v0.z, v0.w, lo, true);
            int hi = __builtin_amdgcn_cvt_pk_fp8_f32(v1.x, v1.y, 0, false);
            hi = __builtin_amdgcn_cvt_pk_fp8_f32(v1.z, v1.w, hi, true);
            int2 o = { lo, hi };
            *(int2*)(o2p8 + i) = o;
        }
    } else if (bid < 2816) {                // packed gate weights
        for (int n = bid - 1792; n < 4096; n += 1024) {
            int cl = n >> 10;
            if (cl < 2) {
                long bb = (long)n * 2560;
                const float* wi = Wih + (long)n * 1536;
                const float* wh = Whh + (long)n * 1024;
                for (int k = tid; k < 1536; k += 256) Wg[bb + k] = f2b(wi[k]);
                for (int k = tid; k < 1024; k += 256) Wg[bb + 1536 + k] = f2b(wh[k]);
            } else if (cl == 2) {
                long bb = 5242880L + (long)(n - 2048) * 1536;
                const float* wi = Wih + (long)n * 1536;
                for (int k = tid; k < 1536; k += 256) Wg[bb + k] = f2b(wi[k]);
            } else {
                long bb = 6815744L + (long)(n - 3072) * 1024;
                const float* wh = Whh + (long)(n - 1024) * 1024;
                for (int k = tid; k < 1024; k += 256) Wg[bb + k] = f2b(wh[k]);
            }
        }
    } else if (bid < 2880) {                // h2oW -> bf16
        for (long i = ((long)(bid - 2816) * 256 + tid) * 4; i < 524288L; i += 65536L) {
            float4 v = *(const float4*)(h2oW + i);
            ushort4 o = { f2b(v.x), f2b(v.y), f2b(v.z), f2b(v.w) };
            *(ushort4*)(h2obf + i) = o;
        }
    } else if (bid < 2944) {                // octxW -> bf16
        for (long i = ((long)(bid - 2880) * 256 + tid) * 4; i < 524288L; i += 65536L) {
            float4 v = *(const float4*)(octxW + i);
            ushort4 o = { f2b(v.x), f2b(v.y), f2b(v.z), f2b(v.w) };
            *(ushort4*)(octxbf + i) = o;
        }
    } else if (bid < 3072) {                // embedding gather -> xc slot0
        for (int r = bid - 2944; r < 1216; r += 128) {
            int row = y[r];
            const float* src = embW + (long)row * 512;
            us* dst = xc + (long)r * 2560;
            for (int e = tid; e < 512; e += 256) dst[e] = f2b(src[e]);
        }
    } else if (bid < 4096) {                // transpose+cvt att_c2c -> c2cT
        int g = bid - 3072;
        int bx = (g & 31) * 32, by = (g >> 5) * 32;
        int x = tid & 31, y0 = tid >> 5;
        for (int yy = y0; yy < 32; yy += 8) tile[yy][x] = att_c2c[(by + yy) * 1024 + bx + x];
        __syncthreads();
        for (int yy = y0; yy < 32; yy += 8) c2cT[(bx + yy) * 1024 + by + x] = f2b(tile[x][yy]);
    } else if (bid < 5120) {                // transpose+cvt att_h2c -> attbf
        int g = bid - 4096;
        int bx = (g & 31) * 32, by = (g >> 5) * 32;
        int x = tid & 31, y0 = tid >> 5;
        for (int yy = y0; yy < 32; yy += 8) tile[yy][x] = att_h2c[(by + yy) * 1024 + bx + x];
        __syncthreads();
        for (int yy = y0; yy < 32; yy += 8) attbf[(bx + yy) * 1024 + by + x] = f2b(tile[x][yy]);
    } else {                                // zero fills
        int zb = bid - 5120;
        if (zb < 32) {                      // hf32 (256 KiB)
            int4* p = (int4*)hf32;
            int i = zb * 256 + tid;
            p[i] = z4; p[i + 8192] = z4;
        } else if (zb < 40) {               // ht_all h0 rows (128 KiB)
            int4* p = (int4*)ht_all;
            int i = (zb - 32) * 256 + tid;
#pragma unroll
            for (int k = 0; k < 4; ++k) p[i + k * 2048] = z4;
        } else if (zb < 56) {               // xc t=0 h-slot (64 chunks x 1024 us)
            int cbase = (zb - 40) * 4;
#pragma unroll
            for (int c = 0; c < 4; ++c) {
                ushort4* p = (ushort4*)(xc + (long)(cbase + c) * 2560 + 1536);
                ushort4 o = {0, 0, 0, 0};
                p[tid] = o;
            }
        } else if (zb < 64) {               // obf_all pad rows
            int4* p = (int4*)(obf_all + 1216L * 512);
            int i = (zb - 56) * 256 + tid;
            p[i] = z4; p[i + 2048] = z4;
        } else if (zb < 68) {               // obf8 pad rows
            int4* p = (int4*)(obf8 + 1216L * 512);
            int i = (zb - 64) * 256 + tid;
            p[i] = z4; p[i + 1024] = z4;
        } else if (zb < 92) {               // o2p8 weight pad rows (384 KiB)
            int4* p = (int4*)(o2p8 + 16384000L);
            int i = (zb - 68) * 256 + tid;
#pragma unroll
            for (int k = 0; k < 4; ++k) p[i + k * 6144] = z4;
        } else {                            // d_out
            if (tid == 0) out[0] = 0.f;
        }
    }
}

// ---------------- ctx_proj GEMM (m97 structure): 128x128 tile, BK=64 ----------
__global__ __launch_bounds__(256) void k_gemm(const us* __restrict__ A,
                                              const us* __restrict__ Bt,
                                              us* __restrict__ Cb) {
    __shared__ us As[8192], Bs[8192];   // 128 rows x 64 elems each
    int tid = threadIdx.x, lane = tid & 63, w = tid >> 6;
    int mr = lane & 15, kb = lane >> 4;
    int bm = blockIdx.x % 98, bn = blockIdx.x / 98;
    long m0 = (long)bm * 128;
    int n0 = bn * 128;
    int wr = w >> 1, wc = w & 1;
    int srow = w * 32 + (lane >> 3);
    int ib = (lane & 7) * 16;

    f32x4 acc[4][4];
#pragma unroll
    for (int i = 0; i < 4; i++)
#pragma unroll
        for (int j = 0; j < 4; j++) acc[i][j] = zero4();

    for (int kt = 0; kt < 16; ++kt) {
        int k0 = kt * 64;
        __syncthreads();
#pragma unroll
        for (int c = 0; c < 4; ++c) {
            int r = srow + c * 8;
            int sw = (ib ^ ((r & 7) << 4)) >> 1;   // element offset within row
            gload_lds16(A + (m0 + r) * 1024 + k0 + sw, &As[w * 2048 + c * 512]);
            gload_lds16(Bt + (long)(n0 + r) * 1024 + k0 + sw, &Bs[w * 2048 + c * 512]);
        }
        __syncthreads();
#pragma unroll
        for (int ks = 0; ks < 2; ++ks) {
            s16x8 af[4], bf[4];
#pragma unroll
            for (int mt = 0; mt < 4; ++mt) {
                int r = wr * 64 + mt * 16 + mr;
                af[mt] = *(const s16x8*)&As[(r * 128 + ((ks * 64 + kb * 16) ^ ((r & 7) << 4))) >> 1];
            }
#pragma unroll
            for (int nt = 0; nt < 4; ++nt) {
                int r = wc * 64 + nt * 16 + mr;
                bf[nt] = *(const s16x8*)&Bs[(r * 128 + ((ks * 64 + kb * 16) ^ ((r & 7) << 4))) >> 1];
            }
#pragma unroll
            for (int mt = 0; mt < 4; ++mt)
#pragma unroll
                for (int nt = 0; nt < 4; ++nt)
                    acc[mt][nt] = MFMA(af[mt], bf[nt], acc[mt][nt]);
        }
    }
#pragma unroll
    for (int mt = 0; mt < 4; ++mt)
#pragma unroll
        for (int nt = 0; nt < 4; ++nt)
#pragma unroll
            for (int j = 0; j < 4; ++j)
                Cb[(m0 + wr * 64 + mt * 16 + kb * 4 + j) * 1024 +
                   n0 + wc * 64 + nt * 16 + mr] = f2b(acc[mt][nt][j]);
}

// ---------------- hproj parts: hpp[kc][b][n] = (h_t @ attT)_Khalf ----------------
__global__ __launch_bounds__(256) void k_hproj(const us* __restrict__ hcur,
                                               const us* __restrict__ attbf,
                                               float* __restrict__ hpp) {
    int tid = threadIdx.x, lane = tid & 63, w = tid >> 6;
    int vn0 = (blockIdx.x >> 1) * 16, kc = blockIdx.x & 1;
    int m0 = w * 16, mr = lane & 15, kb = lane >> 4;
    const us* ap = hcur + (long)(m0 + mr) * 1024 + kc * 512 + kb * 8;
    const us* bp = attbf + (long)(vn0 + mr) * 1024 + kc * 512 + kb * 8;
    f32x4 acc = wg16(ap, bp, 512, zero4());
#pragma unroll
    for (int j = 0; j < 4; ++j)
        hpp[(long)kc * 65536 + (long)(m0 + kb * 4 + j) * 1024 + vn0 + mr] = acc[j];
}

// ---------------- scores: 256 blocks (b x s-quarter), hp staged once ----------
__global__ __launch_bounds__(1024) void k_scores(const us* __restrict__ cpb,
                                                 const float* __restrict__ hpp,
                                                 const float* __restrict__ mlp,
                                                 float* __restrict__ scores) {
    __shared__ float hp[1024];
    __shared__ float ml[1024];
    int tid = threadIdx.x;
    int b = blockIdx.x >> 2, sq = blockIdx.x & 3;
    hp[tid] = hpp[(long)b * 1024 + tid] + hpp[65536 + (long)b * 1024 + tid];
    ml[tid] = mlp[tid];
    __syncthreads();
    int wv = tid >> 6, lane = tid & 63;
    int s0 = sq * 49;
    for (int s = s0 + wv; s < s0 + 49; s += 16) {
        const us* cp = cpb + (long)(s * 64 + b) * 1024 + lane * 16;
        s16x8 c0 = *(const s16x8*)cp;
        s16x8 c1 = *(const s16x8*)(cp + 8);
        int e0 = lane * 16;
        float acc = 0.f;
#pragma unroll
        for (int j = 0; j < 8; ++j)
            acc += fast_tanh(b2f((us)c0[j]) + hp[e0 + j]) * ml[e0 + j];
#pragma unroll
        for (int j = 0; j < 8; ++j)
            acc += fast_tanh(b2f((us)c1[j]) + hp[e0 + 8 + j]) * ml[e0 + 8 + j];
#pragma unroll
        for (int off = 32; off; off >>= 1) acc += __shfl_xor(acc, off, 64);
        if (lane == 0) scores[b * 196 + s] = acc;
    }
}

// ---------------- softmax + z -> xc z-slot; 512 thr, s-split halves ----------
__global__ __launch_bounds__(512) void k_z(const float* __restrict__ scores,
                                           const us* __restrict__ ctxbf,
                                           us* __restrict__ xc, int t) {
    __shared__ float red[512];
    __shared__ float als[196];
    __shared__ float zp[256];
    int tid = threadIdx.x, b = blockIdx.x >> 2, ch = blockIdx.x & 3;
    const float* sc = scores + b * 196;
    float lm = (tid < 196) ? sc[tid] : -1e30f;
    red[tid] = lm; __syncthreads();
    for (int st = 256; st; st >>= 1) { if (tid < st) red[tid] = fmaxf(red[tid], red[tid + st]); __syncthreads(); }
    float m = red[0]; __syncthreads();
    float ls = (tid < 196) ? __expf(sc[tid] - m) : 0.f;
    red[tid] = ls; __syncthreads();
    for (int st = 256; st; st >>= 1) { if (tid < st) red[tid] += red[tid + st]; __syncthreads(); }
    float inv = 1.f / red[0];
    if (tid < 196) als[tid] = ls * inv;
    __syncthreads();
    int c = ch * 256 + (tid & 255);
    int sh = tid >> 8;
    const us* cp = ctxbf + (long)b * 1024 + c;
    float a0 = 0.f;
    int sb = sh * 98;
#pragma unroll 4
    for (int s = sb; s < sb + 98; s += 2) {
        a0 += als[s] * b2f(cp[(long)s * 65536]) +
              als[s + 1] * b2f(cp[(long)(s + 1) * 65536]);
    }
    if (sh) zp[tid & 255] = a0;
    __syncthreads();
    if (!sh) {
        a0 += zp[tid & 255];
        xc[(long)(t * 64 + b) * 2560 + 512 + c] = f2b(a0);
    }
}

// ---------------- fused GRU: all 4 gates + update; XCD-co-located j-tiles -----
__global__ __launch_bounds__(512) void k_gruh2(us* __restrict__ xc,
                                               const us* __restrict__ Wg,
                                               const float* __restrict__ bih,
                                               const float* __restrict__ bhh,
                                               float* __restrict__ hf32,
                                               us* __restrict__ ht_all, int t) {
    __shared__ float lg[2048];   // [g*2+kh][m16][j16]
    int tid = threadIdx.x, lane = tid & 63, w = tid >> 6;
    int mr = lane & 15, kb = lane >> 4;
    int g = w >> 1, kh = w & 1;
    // XCD co-location: the 4 m-subtiles of a j-tile land on one XCD (bid&7)
    int xcd = blockIdx.x & 7, idx = blockIdx.x >> 3;
    int jt = xcd * 8 + (idx >> 2), mq = idx & 3;
    int m0 = mq * 16, j0 = jt * 16;
    const us* xr = xc + (long)t * 163840 + (long)(m0 + mr) * 2560;

    f32x4 acc = zero4();
    if (g == 0) {
        acc = wg16(xr + kh * 1280 + kb * 8,
                   Wg + (long)(j0 + mr) * 2560 + kh * 1280 + kb * 8, 1280, acc);
    } else if (g == 1) {
        acc = wg16(xr + kh * 1280 + kb * 8,
                   Wg + (long)(1024 + j0 + mr) * 2560 + kh * 1280 + kb * 8, 1280, acc);
    } else if (g == 2) {
        acc = wg16(xr + kh * 768 + kb * 8,
                   Wg + 5242880L + (long)(j0 + mr) * 1536 + kh * 768 + kb * 8, 768, acc);
    } else {
        acc = wg16(xr + 1536 + kh * 512 + kb * 8,
                   Wg + 6815744L + (long)(j0 + mr) * 1024 + kh * 512 + kb * 8, 512, acc);
    }
#pragma unroll
    for (int j = 0; j < 4; ++j)
        lg[(g * 2 + kh) * 256 + (kb * 4 + j) * 16 + mr] = acc[j];
    __syncthreads();

    if (tid < 256) {
        int ml = tid >> 4, jj = tid & 15;
        int b = m0 + ml, j = j0 + jj;
        float gr = lg[0 * 256 + ml * 16 + jj] + lg[1 * 256 + ml * 16 + jj];
        float gz = lg[2 * 256 + ml * 16 + jj] + lg[3 * 256 + ml * 16 + jj];
        float gi = lg[4 * 256 + ml * 16 + jj] + lg[5 * 256 + ml * 16 + jj];
        float gh = lg[6 * 256 + ml * 16 + jj] + lg[7 * 256 + ml * 16 + jj];
        float r  = sigmoidf_(gr + bih[j] + bhh[j]);
        float zz = sigmoidf_(gz + bih[1024 + j] + bhh[1024 + j]);
        float n  = fast_tanh(gi + bih[2048 + j] + r * (gh + bhh[2048 + j]));
        float h = (1.f - zz) * n + zz * hf32[b * 1024 + j];
        hf32[b * 1024 + j] = h;
        us hb = f2b(h);
        ht_all[(long)((t + 1) * 64 + b) * 1024 + j] = hb;
        if (t < TS_ - 1) xc[(long)((t + 1) * 64 + b) * 2560 + 1536 + j] = hb;
    }
}

// ---------------- batched output head: 152 blocks (19 m x 8 n of 64) ----------
__global__ __launch_bounds__(256) void k_outb(const us* __restrict__ ht_all,
                                              const us* __restrict__ xc,
                                              const us* __restrict__ h2obf,
                                              const float* __restrict__ h2ob,
                                              const us* __restrict__ octxbf,
                                              const float* __restrict__ octxb,
                                              us* __restrict__ obf_all,
                                              uc* __restrict__ obf8) {
    int tid = threadIdx.x, lane = tid & 63, w = tid >> 6;
    int mr = lane & 15, kb = lane >> 4;
    int m0 = blockIdx.x * 64;
    int n0 = blockIdx.y * 64;
    int e = n0 + w * 16 + mr;
    const us* bb1 = h2obf + (long)e * 1024 + kb * 8;
    const us* bb2 = octxbf + (long)e * 1024 + kb * 8;
    const us* ab1 = ht_all + (long)(64 + m0 + mr) * 1024 + kb * 8;
    const us* ab2 = xc + (long)(m0 + mr) * 2560 + 512 + kb * 8;

    f32x4 a1[4], a2[4];
#pragma unroll
    for (int i = 0; i < 4; i++) { a1[i] = zero4(); a2[i] = zero4(); }

#pragma unroll 2
    for (int k0 = 0; k0 < 1024; k0 += 32) {
        s16x8 b1 = *(const s16x8*)(bb1 + k0);
        s16x8 b2 = *(const s16x8*)(bb2 + k0);
#pragma unroll
        for (int mt = 0; mt < 4; ++mt) {
            a1[mt] = MFMA(*(const s16x8*)(ab1 + mt * 16384 + k0), b1, a1[mt]);
            a2[mt] = MFMA(*(const s16x8*)(ab2 + mt * 40960 + k0), b2, a2[mt]);
        }
    }
    float b1v = h2ob[e], b2v = octxb[e];
#pragma unroll
    for (int mt = 0; mt < 4; ++mt)
#pragma unroll
        for (int j = 0; j < 4; ++j) {
            long row = m0 + mt * 16 + kb * 4 + j;
            float ye = b2f(xc[row * 2560 + e]);
            float val = fast_tanh(fast_tanh(a1[mt][j] + b1v) + ye + a2[mt][j] + b2v);
            obf_all[(row << 9) + e] = f2b(val);
            obf8[(row << 9) + e] = f2e4m3(val);
        }
}

// ---------------- vocab GEMM (fp8, m97 structure) + partial LSE ----------------
__global__ __launch_bounds__(256) void k_vocab8(const uc* __restrict__ obf8,
                                                const uc* __restrict__ o2p8,
                                                const float* __restrict__ o2pb,
                                                float* __restrict__ pm,
                                                float* __restrict__ ps) {
    __shared__ uc As[8192], Bs[8192];   // 128 rows x 64 B each
    int tid = threadIdx.x, lane = tid & 63, w = tid >> 6;
    int mr = lane & 15, kb = lane >> 4;
    int xq = blockIdx.x & 7, idx = blockIdx.x >> 3;
    int nb = xq * 32 + idx / 10, mb = idx % 10;
    int m0 = mb * 128, n0 = nb * 128;
    int wr = w >> 1, wc = w & 1;
    int srow = w * 32 + (lane >> 2);
    int ib = (lane & 3) * 16;

    f32x4 acc[4][4];
#pragma unroll
    for (int i = 0; i < 4; i++)
#pragma unroll
        for (int j = 0; j < 4; j++) acc[i][j] = zero4();

    for (int kt = 0; kt < 8; ++kt) {
        int k0 = kt * 64;
        __syncthreads();
#pragma unroll
        for (int c = 0; c < 2; ++c) {
            int r = srow + c * 16;
            int sw = ib ^ ((r & 6) << 3);
            gload_lds16(obf8 + (long)(m0 + r) * 512 + k0 + sw, &As[w * 2048 + c * 1024]);
            gload_lds16(o2p8 + (long)(n0 + r) * 512 + k0 + sw, &Bs[w * 2048 + c * 1024]);
        }
        __syncthreads();
#pragma unroll
        for (int ks = 0; ks < 2; ++ks) {
            long af[4], bf[4];
#pragma unroll
            for (int mt = 0; mt < 4; ++mt) {
                int r = wr * 64 + mt * 16 + mr;
                af[mt] = *(const long*)&As[r * 64 + ((ks * 32 + kb * 8) ^ ((r & 6) << 3))];
            }
#pragma unroll
            for (int nt = 0; nt < 4; ++nt) {
                int r = wc * 64 + nt * 16 + mr;
                bf[nt] = *(const long*)&Bs[r * 64 + ((ks * 32 + kb * 8) ^ ((r & 6) << 3))];
            }
#pragma unroll
            for (int mt = 0; mt < 4; ++mt)
#pragma unroll
                for (int nt = 0; nt < 4; ++nt)
                    acc[mt][nt] = MFMA8(af[mt], bf[nt], acc[mt][nt]);
        }
    }

    int n0w = n0 + wc * 64;
    float bv[4];
#pragma unroll
    for (int nt = 0; nt < 4; ++nt) {
        int vn = n0w + nt * 16 + mr;
        bv[nt] = (vn < 32000) ? o2pb[vn] : -1e30f;
    }
#pragma unroll
    for (int mt = 0; mt < 4; ++mt)
#pragma unroll
        for (int j = 0; j < 4; ++j) {
            float x0 = acc[mt][0][j] + bv[0];
            float x1 = acc[mt][1][j] + bv[1];
            float x2 = acc[mt][2][j] + bv[2];
            float x3 = acc[mt][3][j] + bv[3];
            float m = fmaxf(fmaxf(x0, x1), fmaxf(x2, x3));
            float s = __expf(x0 - m) + __expf(x1 - m) + __expf(x2 - m) + __expf(x3 - m);
#pragma unroll
            for (int off = 1; off <= 8; off <<= 1) {
                float mo = __shfl_xor(m, off, 64), so = __shfl_xor(s, off, 64);
                float nm = fmaxf(m, mo);
                s = s * __expf(m - nm) + so * __expf(mo - nm);
                m = nm;
            }
            if (mr == 0) {
                int row = m0 + wr * 64 + mt * 16 + kb * 4 + j;
                pm[(long)(nb * 2 + wc) * 1280 + row] = m;
                ps[(long)(nb * 2 + wc) * 1280 + row] = s;
            }
        }
}

// ---------------- final LSE reduce + NLL accumulate ----------------
__global__ __launch_bounds__(64) void k_lseb(const float* __restrict__ pm,
                                             const float* __restrict__ ps,
                                             const us* __restrict__ obf_all,
                                             const float* __restrict__ o2pW,
                                             const float* __restrict__ o2pb,
                                             const int* __restrict__ y,
                                             float* __restrict__ out) {
    int r = blockIdx.x, lane = threadIdx.x;
    int t = r >> 6, b = r & 63;
    int tgt = y[(t + 1) * 64 + b];
    float m = -1e30f, s = 0.f;
    for (int p = lane; p < 512; p += 64) {
        float mi = pm[(long)p * 1280 + r], si = ps[(long)p * 1280 + r];
        float nm = fmaxf(m, mi);
        s = s * __expf(m - nm) + si * __expf(mi - nm);
        m = nm;
    }
#pragma unroll
    for (int off = 32; off; off >>= 1) {
        float mo = __shfl_xor(m, off, 64), so = __shfl_xor(s, off, 64);
        float nm = fmaxf(m, mo);
        s = s * __expf(m - nm) + so * __expf(mo - nm);
        m = nm;
    }
    float d = 0.f;
    const float* wr = o2pW + (long)tgt * 512;
#pragma unroll
    for (int k = 0; k < 8; ++k)
        d += b2f(obf_all[(long)r * 512 + lane + k * 64]) * wr[lane + k * 64];
#pragma unroll
    for (int off = 32; off; off >>= 1) d += __shfl_xor(d, off, 64);
    if (lane == 0 && tgt != 0)
        atomicAdd(out, (m + __logf(s)) - (d + o2pb[tgt]));
}

extern "C" void kernel_launch(void* const* d_in, const int* in_sizes, int n_in,
                              void* d_out, int out_size, void* d_ws, size_t ws_size,
                              hipStream_t stream) {
    const float* ctx     = (const float*)d_in[0];
    const int*   y       = (const int*)d_in[1];
    const float* embW    = (const float*)d_in[2];
    const float* att_c2c = (const float*)d_in[3];
    const float* att_h2c = (const float*)d_in[4];
    const float* mlp     = (const float*)d_in[5];
    const float* Wih     = (const float*)d_in[6];
    const float* bih     = (const float*)d_in[7];
    const float* Whh     = (const float*)d_in[8];
    const float* bhh     = (const float*)d_in[9];
    const float* h2oW    = (const float*)d_in[10];
    const float* h2ob    = (const float*)d_in[11];
    const float* octxW   = (const float*)d_in[12];
    const float* octxb   = (const float*)d_in[13];
    const float* o2pW    = (const float*)d_in[14];
    const float* o2pb    = (const float*)d_in[15];
    float* out = (float*)d_out;

    char* base = (char*)d_ws;
    us* ctxbf   = (us*)base; base += 25690112L;   // [s][b][c] bf16 (= GEMM A)
    us* cpbf    = (us*)base; base += 25690112L;   // [12544][1024]; pm/ps alias after loop
    us* c2cT    = (us*)base; base += 2097152L;
    us* attbf   = (us*)base; base += 2097152L;
    us* Wg      = (us*)base; base += 15728640L;
    us* h2obf   = (us*)base; base += 1048576L;
    us* octxbf  = (us*)base; base += 1048576L;
    uc* o2p8    = (uc*)base; base += 16777216L;   // [32768][512] fp8, rows 32000+ zero
    us* xc      = (us*)base; base += 6225920L;    // [19][64][2560]
    us* ht_all  = (us*)base; base += 2621440L;    // [20*64][1024], rows 0..63 = h0 = 0
    us* obf_all = (us*)base; base += 1310720L;    // [1280][512] bf16, rows 1216+ pad
    uc* obf8    = (uc*)base; base += 655360L;     // [1280][512] fp8
    float* hf32   = (float*)base; base += 262144L;  // [64][1024]
    float* hpp    = (float*)base; base += 524288L;  // [2][64][1024]
    float* scb    = (float*)base; base += 50176L;   // [64][196]
    float* pm   = (float*)cpbf;                   // [512][1280] aliases cpbf (dead by then)
    float* ps   = pm + 655360L;

    // one mega prep kernel: all conversions + packing + zero fills + d_out=0
    k_prep<<<5213, 256, 0, stream>>>(ctx, ctxbf, o2pW, o2p8, Wih, Whh, Wg,
                                     h2oW, h2obf, octxW, octxbf,
                                     att_c2c, c2cT, att_h2c, attbf,
                                     y, embW, xc, hf32, ht_all, obf_all, obf8, out);
    k_gemm<<<784, 256, 0, stream>>>(ctxbf, c2cT, cpbf);

    // sequential recurrence: 4 kernels per step
    for (int t = 0; t < TS_; t++) {
        k_hproj<<<128, 256, 0, stream>>>(ht_all + (long)t * 65536, attbf, hpp);
        k_scores<<<256, 1024, 0, stream>>>(cpbf, hpp, mlp, scb);
        k_z<<<256, 512, 0, stream>>>(scb, ctxbf, xc, t);
        k_gruh2<<<256, 512, 0, stream>>>(xc, Wg, bih, bhh, hf32, ht_all, t);
    }

    // deferred output head, batched over all steps
    k_outb<<<dim3(19, 8), 256, 0, stream>>>(ht_all, xc, h2obf, h2ob, octxbf, octxb,
                                            obf_all, obf8);
    k_vocab8<<<2560, 256, 0, stream>>>(obf8, o2p8, o2pb, pm, ps);
    k_lseb<<<1216, 64, 0, stream>>>(pm, ps, obf_all, o2pW, o2pb, y, out);
}

// Round 16
// 982.338 us; speedup vs baseline: 1.1933x; 1.0004x over previous
//
#include <hip/hip_runtime.h>
#include <math.h>

#define TS_ 19   // T-1 decode steps

typedef float f32x4 __attribute__((ext_vector_type(4)));
typedef short s16x8 __attribute__((ext_vector_type(8)));
typedef unsigned short us;
typedef unsigned char uc;

__device__ __forceinline__ float sigmoidf_(float x) { return 1.f / (1.f + __expf(-x)); }

__device__ __forceinline__ float fast_tanh(float x) {
    float ax = fabsf(x);
    float e = __expf(-2.f * ax);
    float r = (1.f - e) * __builtin_amdgcn_rcpf(1.f + e);
    return copysignf(r, x);
}

__device__ __forceinline__ us f2b(float x) {
    union { float f; unsigned u; } v; v.f = x;
    unsigned r = v.u + 0x7fffu + ((v.u >> 16) & 1u);
    return (us)(r >> 16);
}
__device__ __forceinline__ float b2f(us u) {
    union { unsigned u; float f; } v; v.u = ((unsigned)u) << 16; return v.f;
}
__device__ __forceinline__ uc f2e4m3(float x) {
    return (uc)(__builtin_amdgcn_cvt_pk_fp8_f32(x, 0.f, 0, false) & 0xff);
}

#define MFMA(a, b, c) __builtin_amdgcn_mfma_f32_16x16x32_bf16((a), (b), (c), 0, 0, 0)
#define MFMA8(a, b, c) __builtin_amdgcn_mfma_f32_16x16x32_fp8_fp8((a), (b), (c), 0, 0, 0)

__device__ __forceinline__ f32x4 zero4() { return (f32x4){0.f, 0.f, 0.f, 0.f}; }

__device__ __forceinline__ f32x4 wg16(const us* ap, const us* bp, int nk, f32x4 acc) {
#pragma unroll 4
    for (int k = 0; k < nk; k += 32)
        acc = MFMA(*(const s16x8*)(ap + k), *(const s16x8*)(bp + k), acc);
    return acc;
}

// async global -> LDS, 16B per lane; dest = wave-uniform base + lane*16
__device__ __forceinline__ void gload_lds16(const void* g, void* l) {
    __builtin_amdgcn_global_load_lds(
        (const __attribute__((address_space(1))) unsigned int*)g,
        (__attribute__((address_space(3))) unsigned int*)l, 16, 0, 0);
}

__device__ __forceinline__ void cvt4(const float* src, us* dst) {
    float4 v = *(const float4*)src;
    ushort4 o = { f2b(v.x), f2b(v.y), f2b(v.z), f2b(v.w) };
    *(ushort4*)dst = o;
}

// ---------------- mega prep: all conversions + weight packing + zero fills -----
__global__ __launch_bounds__(256) void k_prep(
    const float* __restrict__ ctx, us* __restrict__ ctxbf,
    const float* __restrict__ o2pW, uc* __restrict__ o2p8,
    const float* __restrict__ Wih, const float* __restrict__ Whh, us* __restrict__ Wg,
    const float* __restrict__ h2oW, us* __restrict__ h2obf,
    const float* __restrict__ octxW, us* __restrict__ octxbf,
    const float* __restrict__ att_c2c, us* __restrict__ c2cT,
    const float* __restrict__ att_h2c, us* __restrict__ attbf,
    const int* __restrict__ y, const float* __restrict__ embW, us* __restrict__ xc,
    float* __restrict__ hf32, us* __restrict__ ht_all,
    us* __restrict__ obf_all, uc* __restrict__ obf8, float* __restrict__ out) {
    __shared__ float tile[32][33];
    int bid = blockIdx.x, tid = threadIdx.x;
    const int4 z4 = {0, 0, 0, 0};

    if (bid < 1024) {                       // ctx -> bf16
        for (long i = ((long)bid * 256 + tid) * 4; i < 12845056L; i += 1048576L)
            cvt4(ctx + i, ctxbf + i);
    } else if (bid < 1792) {                // o2pW -> fp8
        for (long i = ((long)(bid - 1024) * 256 + tid) * 8; i < 16384000L;
             i += 1572864L) {
            float4 v0 = *(const float4*)(o2pW + i);
            float4 v1 = *(const float4*)(o2pW + i + 4);
            int lo = __builtin_amdgcn_cvt_pk_fp8_f32(v0.x, v0.y, 0, false);
            lo = __builtin_amdgcn_cvt_pk_fp8_f32(v0.z, v0.w, lo, true);
            int hi = __builtin_amdgcn_cvt_pk_fp8_f32(v1.x, v1.y, 0, false);
            hi = __builtin_amdgcn_cvt_pk_fp8_f32(v1.z, v1.w, hi, true);
            int2 o = { lo, hi };
            *(int2*)(o2p8 + i) = o;
        }
    } else if (bid < 2304) {                // packed gate weights (vectorized)
        for (int n = bid - 1792; n < 4096; n += 512) {
            int cl = n >> 10;
            if (cl < 2) {
                us* wb = Wg + (long)n * 2560;
                const float* wi = Wih + (long)n * 1536;
                const float* wh = Whh + (long)n * 1024;
                for (int k4 = tid; k4 < 384; k4 += 256) cvt4(wi + k4 * 4, wb + k4 * 4);
                if (tid < 256)
                    cvt4(wh + tid * 4, wb + 1536 + tid * 4);
            } else if (cl == 2) {
                us* wb = Wg + 5242880L + (long)(n - 2048) * 1536;
                const float* wi = Wih + (long)n * 1536;
                for (int k4 = tid; k4 < 384; k4 += 256) cvt4(wi + k4 * 4, wb + k4 * 4);
            } else {
                us* wb = Wg + 6815744L + (long)(n - 3072) * 1024;
                const float* wh = Whh + (long)(n - 1024) * 1024;
                cvt4(wh + tid * 4, wb + tid * 4);
            }
        }
    } else if (bid < 2368) {                // h2oW -> bf16
        for (long i = ((long)(bid - 2304) * 256 + tid) * 4; i < 524288L; i += 65536L)
            cvt4(h2oW + i, h2obf + i);
    } else if (bid < 2432) {                // octxW -> bf16
        for (long i = ((long)(bid - 2368) * 256 + tid) * 4; i < 524288L; i += 65536L)
            cvt4(octxW + i, octxbf + i);
    } else if (bid < 2560) {                // embedding gather -> xc slot0
        for (int r = bid - 2432; r < 1216; r += 128) {
            int row = y[r];
            const float* src = embW + (long)row * 512;
            us* dst = xc + (long)r * 2560;
            for (int e = tid; e < 512; e += 256) dst[e] = f2b(src[e]);
        }
    } else if (bid < 3584) {                // transpose+cvt att_c2c -> c2cT
        int g = bid - 2560;
        int bx = (g & 31) * 32, by = (g >> 5) * 32;
        int x = tid & 31, y0 = tid >> 5;
        for (int yy = y0; yy < 32; yy += 8) tile[yy][x] = att_c2c[(by + yy) * 1024 + bx + x];
        __syncthreads();
        for (int yy = y0; yy < 32; yy += 8) c2cT[(bx + yy) * 1024 + by + x] = f2b(tile[x][yy]);
    } else if (bid < 4608) {                // transpose+cvt att_h2c -> attbf
        int g = bid - 3584;
        int bx = (g & 31) * 32, by = (g >> 5) * 32;
        int x = tid & 31, y0 = tid >> 5;
        for (int yy = y0; yy < 32; yy += 8) tile[yy][x] = att_h2c[(by + yy) * 1024 + bx + x];
        __syncthreads();
        for (int yy = y0; yy < 32; yy += 8) attbf[(bx + yy) * 1024 + by + x] = f2b(tile[x][yy]);
    } else {                                // zero fills
        int zb = bid - 4608;
        if (zb < 32) {                      // hf32 (256 KiB)
            int4* p = (int4*)hf32;
            int i = zb * 256 + tid;
            p[i] = z4; p[i + 8192] = z4;
        } else if (zb < 40) {               // ht_all h0 rows (128 KiB)
            int4* p = (int4*)ht_all;
            int i = (zb - 32) * 256 + tid;
#pragma unroll
            for (int k = 0; k < 4; ++k) p[i + k * 2048] = z4;
        } else if (zb < 56) {               // xc t=0 h-slot (64 chunks x 1024 us)
            int cbase = (zb - 40) * 4;
#pragma unroll
            for (int c = 0; c < 4; ++c) {
                ushort4* p = (ushort4*)(xc + (long)(cbase + c) * 2560 + 1536);
                ushort4 o = {0, 0, 0, 0};
                p[tid] = o;
            }
        } else if (zb < 64) {               // obf_all pad rows
            int4* p = (int4*)(obf_all + 1216L * 512);
            int i = (zb - 56) * 256 + tid;
            p[i] = z4; p[i + 2048] = z4;
        } else if (zb < 68) {               // obf8 pad rows
            int4* p = (int4*)(obf8 + 1216L * 512);
            int i = (zb - 64) * 256 + tid;
            p[i] = z4; p[i + 1024] = z4;
        } else if (zb < 92) {               // o2p8 weight pad rows (384 KiB)
            int4* p = (int4*)(o2p8 + 16384000L);
            int i = (zb - 68) * 256 + tid;
#pragma unroll
            for (int k = 0; k < 4; ++k) p[i + k * 6144] = z4;
        } else {                            // d_out
            if (tid == 0) out[0] = 0.f;
        }
    }
}

// ---------------- ctx_proj GEMM (m97 structure): 128x128 tile, BK=64 ----------
__global__ __launch_bounds__(256) void k_gemm(const us* __restrict__ A,
                                              const us* __restrict__ Bt,
                                              us* __restrict__ Cb) {
    __shared__ us As[8192], Bs[8192];   // 128 rows x 64 elems each
    int tid = threadIdx.x, lane = tid & 63, w = tid >> 6;
    int mr = lane & 15, kb = lane >> 4;
    int bm = blockIdx.x % 98, bn = blockIdx.x / 98;
    long m0 = (long)bm * 128;
    int n0 = bn * 128;
    int wr = w >> 1, wc = w & 1;
    int srow = w * 32 + (lane >> 3);
    int ib = (lane & 7) * 16;

    f32x4 acc[4][4];
#pragma unroll
    for (int i = 0; i < 4; i++)
#pragma unroll
        for (int j = 0; j < 4; j++) acc[i][j] = zero4();

    for (int kt = 0; kt < 16; ++kt) {
        int k0 = kt * 64;
        __syncthreads();
#pragma unroll
        for (int c = 0; c < 4; ++c) {
            int r = srow + c * 8;
            int sw = (ib ^ ((r & 7) << 4)) >> 1;   // element offset within row
            gload_lds16(A + (m0 + r) * 1024 + k0 + sw, &As[w * 2048 + c * 512]);
            gload_lds16(Bt + (long)(n0 + r) * 1024 + k0 + sw, &Bs[w * 2048 + c * 512]);
        }
        __syncthreads();
#pragma unroll
        for (int ks = 0; ks < 2; ++ks) {
            s16x8 af[4], bf[4];
#pragma unroll
            for (int mt = 0; mt < 4; ++mt) {
                int r = wr * 64 + mt * 16 + mr;
                af[mt] = *(const s16x8*)&As[(r * 128 + ((ks * 64 + kb * 16) ^ ((r & 7) << 4))) >> 1];
            }
#pragma unroll
            for (int nt = 0; nt < 4; ++nt) {
                int r = wc * 64 + nt * 16 + mr;
                bf[nt] = *(const s16x8*)&Bs[(r * 128 + ((ks * 64 + kb * 16) ^ ((r & 7) << 4))) >> 1];
            }
#pragma unroll
            for (int mt = 0; mt < 4; ++mt)
#pragma unroll
                for (int nt = 0; nt < 4; ++nt)
                    acc[mt][nt] = MFMA(af[mt], bf[nt], acc[mt][nt]);
        }
    }
#pragma unroll
    for (int mt = 0; mt < 4; ++mt)
#pragma unroll
        for (int nt = 0; nt < 4; ++nt)
#pragma unroll
            for (int j = 0; j < 4; ++j)
                Cb[(m0 + wr * 64 + mt * 16 + kb * 4 + j) * 1024 +
                   n0 + wc * 64 + nt * 16 + mr] = f2b(acc[mt][nt][j]);
}

// ---------------- hproj parts: hpp[kc][b][n] = (h_t @ attT)_Khalf ----------------
__global__ __launch_bounds__(256) void k_hproj(const us* __restrict__ hcur,
                                               const us* __restrict__ attbf,
                                               float* __restrict__ hpp) {
    int tid = threadIdx.x, lane = tid & 63, w = tid >> 6;
    int vn0 = (blockIdx.x >> 1) * 16, kc = blockIdx.x & 1;
    int m0 = w * 16, mr = lane & 15, kb = lane >> 4;
    const us* ap = hcur + (long)(m0 + mr) * 1024 + kc * 512 + kb * 8;
    const us* bp = attbf + (long)(vn0 + mr) * 1024 + kc * 512 + kb * 8;
    f32x4 acc = wg16(ap, bp, 512, zero4());
#pragma unroll
    for (int j = 0; j < 4; ++j)
        hpp[(long)kc * 65536 + (long)(m0 + kb * 4 + j) * 1024 + vn0 + mr] = acc[j];
}

// ---------------- scores: 256 blocks (b x s-quarter), hp staged once ----------
__global__ __launch_bounds__(1024) void k_scores(const us* __restrict__ cpb,
                                                 const float* __restrict__ hpp,
                                                 const float* __restrict__ mlp,
                                                 float* __restrict__ scores) {
    __shared__ float hp[1024];
    __shared__ float ml[1024];
    int tid = threadIdx.x;
    int b = blockIdx.x >> 2, sq = blockIdx.x & 3;
    hp[tid] = hpp[(long)b * 1024 + tid] + hpp[65536 + (long)b * 1024 + tid];
    ml[tid] = mlp[tid];
    __syncthreads();
    int wv = tid >> 6, lane = tid & 63;
    int s0 = sq * 49;
    for (int s = s0 + wv; s < s0 + 49; s += 16) {
        const us* cp = cpb + (long)(s * 64 + b) * 1024 + lane * 16;
        s16x8 c0 = *(const s16x8*)cp;
        s16x8 c1 = *(const s16x8*)(cp + 8);
        int e0 = lane * 16;
        float acc = 0.f;
#pragma unroll
        for (int j = 0; j < 8; ++j)
            acc += fast_tanh(b2f((us)c0[j]) + hp[e0 + j]) * ml[e0 + j];
#pragma unroll
        for (int j = 0; j < 8; ++j)
            acc += fast_tanh(b2f((us)c1[j]) + hp[e0 + 8 + j]) * ml[e0 + 8 + j];
#pragma unroll
        for (int off = 32; off; off >>= 1) acc += __shfl_xor(acc, off, 64);
        if (lane == 0) scores[b * 196 + s] = acc;
    }
}

// ---------------- softmax + z -> xc z-slot; 512 thr, s-split halves ----------
__global__ __launch_bounds__(512) void k_z(const float* __restrict__ scores,
                                           const us* __restrict__ ctxbf,
                                           us* __restrict__ xc, int t) {
    __shared__ float red[512];
    __shared__ float als[196];
    __shared__ float zp[256];
    int tid = threadIdx.x, b = blockIdx.x >> 2, ch = blockIdx.x & 3;
    const float* sc = scores + b * 196;
    float lm = (tid < 196) ? sc[tid] : -1e30f;
    red[tid] = lm; __syncthreads();
    for (int st = 256; st; st >>= 1) { if (tid < st) red[tid] = fmaxf(red[tid], red[tid + st]); __syncthreads(); }
    float m = red[0]; __syncthreads();
    float ls = (tid < 196) ? __expf(sc[tid] - m) : 0.f;
    red[tid] = ls; __syncthreads();
    for (int st = 256; st; st >>= 1) { if (tid < st) red[tid] += red[tid + st]; __syncthreads(); }
    float inv = 1.f / red[0];
    if (tid < 196) als[tid] = ls * inv;
    __syncthreads();
    int c = ch * 256 + (tid & 255);
    int sh = tid >> 8;
    const us* cp = ctxbf + (long)b * 1024 + c;
    float a0 = 0.f;
    int sb = sh * 98;
#pragma unroll 4
    for (int s = sb; s < sb + 98; s += 2) {
        a0 += als[s] * b2f(cp[(long)s * 65536]) +
              als[s + 1] * b2f(cp[(long)(s + 1) * 65536]);
    }
    if (sh) zp[tid & 255] = a0;
    __syncthreads();
    if (!sh) {
        a0 += zp[tid & 255];
        xc[(long)(t * 64 + b) * 2560 + 512 + c] = f2b(a0);
    }
}

// ---------------- fused GRU: all 4 gates + update; XCD-co-located j-tiles -----
__global__ __launch_bounds__(512) void k_gruh2(us* __restrict__ xc,
                                               const us* __restrict__ Wg,
                                               const float* __restrict__ bih,
                                               const float* __restrict__ bhh,
                                               float* __restrict__ hf32,
                                               us* __restrict__ ht_all, int t) {
    __shared__ float lg[2048];   // [g*2+kh][m16][j16]
    int tid = threadIdx.x, lane = tid & 63, w = tid >> 6;
    int mr = lane & 15, kb = lane >> 4;
    int g = w >> 1, kh = w & 1;
    // XCD co-location: the 4 m-subtiles of a j-tile land on one XCD (bid&7)
    int xcd = blockIdx.x & 7, idx = blockIdx.x >> 3;
    int jt = xcd * 8 + (idx >> 2), mq = idx & 3;
    int m0 = mq * 16, j0 = jt * 16;
    const us* xr = xc + (long)t * 163840 + (long)(m0 + mr) * 2560;

    f32x4 acc = zero4();
    if (g == 0) {
        acc = wg16(xr + kh * 1280 + kb * 8,
                   Wg + (long)(j0 + mr) * 2560 + kh * 1280 + kb * 8, 1280, acc);
    } else if (g == 1) {
        acc = wg16(xr + kh * 1280 + kb * 8,
                   Wg + (long)(1024 + j0 + mr) * 2560 + kh * 1280 + kb * 8, 1280, acc);
    } else if (g == 2) {
        acc = wg16(xr + kh * 768 + kb * 8,
                   Wg + 5242880L + (long)(j0 + mr) * 1536 + kh * 768 + kb * 8, 768, acc);
    } else {
        acc = wg16(xr + 1536 + kh * 512 + kb * 8,
                   Wg + 6815744L + (long)(j0 + mr) * 1024 + kh * 512 + kb * 8, 512, acc);
    }
#pragma unroll
    for (int j = 0; j < 4; ++j)
        lg[(g * 2 + kh) * 256 + (kb * 4 + j) * 16 + mr] = acc[j];
    __syncthreads();

    if (tid < 256) {
        int ml = tid >> 4, jj = tid & 15;
        int b = m0 + ml, j = j0 + jj;
        float gr = lg[0 * 256 + ml * 16 + jj] + lg[1 * 256 + ml * 16 + jj];
        float gz = lg[2 * 256 + ml * 16 + jj] + lg[3 * 256 + ml * 16 + jj];
        float gi = lg[4 * 256 + ml * 16 + jj] + lg[5 * 256 + ml * 16 + jj];
        float gh = lg[6 * 256 + ml * 16 + jj] + lg[7 * 256 + ml * 16 + jj];
        float r  = sigmoidf_(gr + bih[j] + bhh[j]);
        float zz = sigmoidf_(gz + bih[1024 + j] + bhh[1024 + j]);
        float n  = fast_tanh(gi + bih[2048 + j] + r * (gh + bhh[2048 + j]));
        float h = (1.f - zz) * n + zz * hf32[b * 1024 + j];
        hf32[b * 1024 + j] = h;
        us hb = f2b(h);
        ht_all[(long)((t + 1) * 64 + b) * 1024 + j] = hb;
        if (t < TS_ - 1) xc[(long)((t + 1) * 64 + b) * 2560 + 1536 + j] = hb;
    }
}

// ---------------- batched output head: 152 blocks (19 m x 8 n of 64) ----------
__global__ __launch_bounds__(256) void k_outb(const us* __restrict__ ht_all,
                                              const us* __restrict__ xc,
                                              const us* __restrict__ h2obf,
                                              const float* __restrict__ h2ob,
                                              const us* __restrict__ octxbf,
                                              const float* __restrict__ octxb,
                                              us* __restrict__ obf_all,
                                              uc* __restrict__ obf8) {
    int tid = threadIdx.x, lane = tid & 63, w = tid >> 6;
    int mr = lane & 15, kb = lane >> 4;
    int m0 = blockIdx.x * 64;
    int n0 = blockIdx.y * 64;
    int e = n0 + w * 16 + mr;
    const us* bb1 = h2obf + (long)e * 1024 + kb * 8;
    const us* bb2 = octxbf + (long)e * 1024 + kb * 8;
    const us* ab1 = ht_all + (long)(64 + m0 + mr) * 1024 + kb * 8;
    const us* ab2 = xc + (long)(m0 + mr) * 2560 + 512 + kb * 8;

    f32x4 a1[4], a2[4];
#pragma unroll
    for (int i = 0; i < 4; i++) { a1[i] = zero4(); a2[i] = zero4(); }

#pragma unroll 2
    for (int k0 = 0; k0 < 1024; k0 += 32) {
        s16x8 b1 = *(const s16x8*)(bb1 + k0);
        s16x8 b2 = *(const s16x8*)(bb2 + k0);
#pragma unroll
        for (int mt = 0; mt < 4; ++mt) {
            a1[mt] = MFMA(*(const s16x8*)(ab1 + mt * 16384 + k0), b1, a1[mt]);
            a2[mt] = MFMA(*(const s16x8*)(ab2 + mt * 40960 + k0), b2, a2[mt]);
        }
    }
    float b1v = h2ob[e], b2v = octxb[e];
#pragma unroll
    for (int mt = 0; mt < 4; ++mt)
#pragma unroll
        for (int j = 0; j < 4; ++j) {
            long row = m0 + mt * 16 + kb * 4 + j;
            float ye = b2f(xc[row * 2560 + e]);
            float val = fast_tanh(fast_tanh(a1[mt][j] + b1v) + ye + a2[mt][j] + b2v);
            obf_all[(row << 9) + e] = f2b(val);
            obf8[(row << 9) + e] = f2e4m3(val);
        }
}

// ---------------- vocab GEMM (fp8, dbuf LDS, 1 barrier/K-tile) + partial LSE ---
__global__ __launch_bounds__(256) void k_vocab8(const uc* __restrict__ obf8,
                                                const uc* __restrict__ o2p8,
                                                const float* __restrict__ o2pb,
                                                float* __restrict__ pm,
                                                float* __restrict__ ps) {
    __shared__ uc As[2][8192], Bs[2][8192];   // dbuf: 128 rows x 64 B each
    int tid = threadIdx.x, lane = tid & 63, w = tid >> 6;
    int mr = lane & 15, kb = lane >> 4;
    int xq = blockIdx.x & 7, idx = blockIdx.x >> 3;
    int nb = xq * 32 + idx / 10, mb = idx % 10;
    int m0 = mb * 128, n0 = nb * 128;
    int wr = w >> 1, wc = w & 1;
    int srow = w * 32 + (lane >> 2);
    int ib = (lane & 3) * 16;

    f32x4 acc[4][4];
#pragma unroll
    for (int i = 0; i < 4; i++)
#pragma unroll
        for (int j = 0; j < 4; j++) acc[i][j] = zero4();

    // prologue: stage kt=0 into buf 0
#pragma unroll
    for (int c = 0; c < 2; ++c) {
        int r = srow + c * 16;
        int sw = ib ^ ((r & 6) << 3);
        gload_lds16(obf8 + (long)(m0 + r) * 512 + sw, &As[0][w * 2048 + c * 1024]);
        gload_lds16(o2p8 + (long)(n0 + r) * 512 + sw, &Bs[0][w * 2048 + c * 1024]);
    }
    __syncthreads();

    int buf = 0;
    for (int kt = 0; kt < 8; ++kt) {
        if (kt < 7) {
            int k1 = (kt + 1) * 64;
#pragma unroll
            for (int c = 0; c < 2; ++c) {
                int r = srow + c * 16;
                int sw = ib ^ ((r & 6) << 3);
                gload_lds16(obf8 + (long)(m0 + r) * 512 + k1 + sw,
                            &As[buf ^ 1][w * 2048 + c * 1024]);
                gload_lds16(o2p8 + (long)(n0 + r) * 512 + k1 + sw,
                            &Bs[buf ^ 1][w * 2048 + c * 1024]);
            }
        }
#pragma unroll
        for (int ks = 0; ks < 2; ++ks) {
            long af[4], bf[4];
#pragma unroll
            for (int mt = 0; mt < 4; ++mt) {
                int r = wr * 64 + mt * 16 + mr;
                af[mt] = *(const long*)&As[buf][r * 64 + ((ks * 32 + kb * 8) ^ ((r & 6) << 3))];
            }
#pragma unroll
            for (int nt = 0; nt < 4; ++nt) {
                int r = wc * 64 + nt * 16 + mr;
                bf[nt] = *(const long*)&Bs[buf][r * 64 + ((ks * 32 + kb * 8) ^ ((r & 6) << 3))];
            }
#pragma unroll
            for (int mt = 0; mt < 4; ++mt)
#pragma unroll
                for (int nt = 0; nt < 4; ++nt)
                    acc[mt][nt] = MFMA8(af[mt], bf[nt], acc[mt][nt]);
        }
        __syncthreads();   // drains vmcnt -> buf^1 staged; LDS reuse safe
        buf ^= 1;
    }

    int n0w = n0 + wc * 64;
    float bv[4];
#pragma unroll
    for (int nt = 0; nt < 4; ++nt) {
        int vn = n0w + nt * 16 + mr;
        bv[nt] = (vn < 32000) ? o2pb[vn] : -1e30f;
    }
#pragma unroll
    for (int mt = 0; mt < 4; ++mt)
#pragma unroll
        for (int j = 0; j < 4; ++j) {
            float x0 = acc[mt][0][j] + bv[0];
            float x1 = acc[mt][1][j] + bv[1];
            float x2 = acc[mt][2][j] + bv[2];
            float x3 = acc[mt][3][j] + bv[3];
            float m = fmaxf(fmaxf(x0, x1), fmaxf(x2, x3));
            float s = __expf(x0 - m) + __expf(x1 - m) + __expf(x2 - m) + __expf(x3 - m);
#pragma unroll
            for (int off = 1; off <= 8; off <<= 1) {
                float mo = __shfl_xor(m, off, 64), so = __shfl_xor(s, off, 64);
                float nm = fmaxf(m, mo);
                s = s * __expf(m - nm) + so * __expf(mo - nm);
                m = nm;
            }
            if (mr == 0) {
                int row = m0 + wr * 64 + mt * 16 + kb * 4 + j;
                pm[(long)(nb * 2 + wc) * 1280 + row] = m;
                ps[(long)(nb * 2 + wc) * 1280 + row] = s;
            }
        }
}

// ---------------- final LSE reduce + NLL accumulate ----------------
__global__ __launch_bounds__(64) void k_lseb(const float* __restrict__ pm,
                                             const float* __restrict__ ps,
                                             const us* __restrict__ obf_all,
                                             const float* __restrict__ o2pW,
                                             const float* __restrict__ o2pb,
                                             const int* __restrict__ y,
                                             float* __restrict__ out) {
    int r = blockIdx.x, lane = threadIdx.x;
    int t = r >> 6, b = r & 63;
    int tgt = y[(t + 1) * 64 + b];
    float m = -1e30f, s = 0.f;
    for (int p = lane; p < 512; p += 64) {
        float mi = pm[(long)p * 1280 + r], si = ps[(long)p * 1280 + r];
        float nm = fmaxf(m, mi);
        s = s * __expf(m - nm) + si * __expf(mi - nm);
        m = nm;
    }
#pragma unroll
    for (int off = 32; off; off >>= 1) {
        float mo = __shfl_xor(m, off, 64), so = __shfl_xor(s, off, 64);
        float nm = fmaxf(m, mo);
        s = s * __expf(m - nm) + so * __expf(mo - nm);
        m = nm;
    }
    float d = 0.f;
    const float* wr = o2pW + (long)tgt * 512;
#pragma unroll
    for (int k = 0; k < 8; ++k)
        d += b2f(obf_all[(long)r * 512 + lane + k * 64]) * wr[lane + k * 64];
#pragma unroll
    for (int off = 32; off; off >>= 1) d += __shfl_xor(d, off, 64);
    if (lane == 0 && tgt != 0)
        atomicAdd(out, (m + __logf(s)) - (d + o2pb[tgt]));
}

extern "C" void kernel_launch(void* const* d_in, const int* in_sizes, int n_in,
                              void* d_out, int out_size, void* d_ws, size_t ws_size,
                              hipStream_t stream) {
    const float* ctx     = (const float*)d_in[0];
    const int*   y       = (const int*)d_in[1];
    const float* embW    = (const float*)d_in[2];
    const float* att_c2c = (const float*)d_in[3];
    const float* att_h2c = (const float*)d_in[4];
    const float* mlp     = (const float*)d_in[5];
    const float* Wih     = (const float*)d_in[6];
    const float* bih     = (const float*)d_in[7];
    const float* Whh     = (const float*)d_in[8];
    const float* bhh     = (const float*)d_in[9];
    const float* h2oW    = (const float*)d_in[10];
    const float* h2ob    = (const float*)d_in[11];
    const float* octxW   = (const float*)d_in[12];
    const float* octxb   = (const float*)d_in[13];
    const float* o2pW    = (const float*)d_in[14];
    const float* o2pb    = (const float*)d_in[15];
    float* out = (float*)d_out;

    char* base = (char*)d_ws;
    us* ctxbf   = (us*)base; base += 25690112L;   // [s][b][c] bf16 (= GEMM A)
    us* cpbf    = (us*)base; base += 25690112L;   // [12544][1024]; pm/ps alias after loop
    us* c2cT    = (us*)base; base += 2097152L;
    us* attbf   = (us*)base; base += 2097152L;
    us* Wg      = (us*)base; base += 15728640L;
    us* h2obf   = (us*)base; base += 1048576L;
    us* octxbf  = (us*)base; base += 1048576L;
    uc* o2p8    = (uc*)base; base += 16777216L;   // [32768][512] fp8, rows 32000+ zero
    us* xc      = (us*)base; base += 6225920L;    // [19][64][2560]
    us* ht_all  = (us*)base; base += 2621440L;    // [20*64][1024], rows 0..63 = h0 = 0
    us* obf_all = (us*)base; base += 1310720L;    // [1280][512] bf16, rows 1216+ pad
    uc* obf8    = (uc*)base; base += 655360L;     // [1280][512] fp8
    float* hf32   = (float*)base; base += 262144L;  // [64][1024]
    float* hpp    = (float*)base; base += 524288L;  // [2][64][1024]
    float* scb    = (float*)base; base += 50176L;   // [64][196]
    float* pm   = (float*)cpbf;                   // [512][1280] aliases cpbf (dead by then)
    float* ps   = pm + 655360L;

    // one mega prep kernel: all conversions + packing + zero fills + d_out=0
    k_prep<<<4701, 256, 0, stream>>>(ctx, ctxbf, o2pW, o2p8, Wih, Whh, Wg,
                                     h2oW, h2obf, octxW, octxbf,
                                     att_c2c, c2cT, att_h2c, attbf,
                                     y, embW, xc, hf32, ht_all, obf_all, obf8, out);
    k_gemm<<<784, 256, 0, stream>>>(ctxbf, c2cT, cpbf);

    // sequential recurrence: 4 kernels per step
    for (int t = 0; t < TS_; t++) {
        k_hproj<<<128, 256, 0, stream>>>(ht_all + (long)t * 65536, attbf, hpp);
        k_scores<<<256, 1024, 0, stream>>>(cpbf, hpp, mlp, scb);
        k_z<<<256, 512, 0, stream>>>(scb, ctxbf, xc, t);
        k_gruh2<<<256, 512, 0, stream>>>(xc, Wg, bih, bhh, hf32, ht_all, t);
    }

    // deferred output head, batched over all steps
    k_outb<<<dim3(19, 8), 256, 0, stream>>>(ht_all, xc, h2obf, h2ob, octxbf, octxb,
                                            obf_all, obf8);
    k_vocab8<<<2560, 256, 0, stream>>>(obf8, o2p8, o2pb, pm, ps);
    k_lseb<<<1216, 64, 0, stream>>>(pm, ps, obf_all, o2pW, o2pb, y, out);
}

// Round 17
// 980.302 us; speedup vs baseline: 1.1957x; 1.0021x over previous
//
#include <hip/hip_runtime.h>
#include <math.h>

#define TS_ 19   // T-1 decode steps

typedef float f32x4 __attribute__((ext_vector_type(4)));
typedef short s16x8 __attribute__((ext_vector_type(8)));
typedef unsigned short us;
typedef unsigned char uc;

__device__ __forceinline__ float sigmoidf_(float x) { return 1.f / (1.f + __expf(-x)); }

__device__ __forceinline__ float fast_tanh(float x) {
    float ax = fabsf(x);
    float e = __expf(-2.f * ax);
    float r = (1.f - e) * __builtin_amdgcn_rcpf(1.f + e);
    return copysignf(r, x);
}

__device__ __forceinline__ us f2b(float x) {
    union { float f; unsigned u; } v; v.f = x;
    unsigned r = v.u + 0x7fffu + ((v.u >> 16) & 1u);
    return (us)(r >> 16);
}
__device__ __forceinline__ float b2f(us u) {
    union { unsigned u; float f; } v; v.u = ((unsigned)u) << 16; return v.f;
}
__device__ __forceinline__ uc f2e4m3(float x) {
    return (uc)(__builtin_amdgcn_cvt_pk_fp8_f32(x, 0.f, 0, false) & 0xff);
}

#define MFMA(a, b, c) __builtin_amdgcn_mfma_f32_16x16x32_bf16((a), (b), (c), 0, 0, 0)
#define MFMA8(a, b, c) __builtin_amdgcn_mfma_f32_16x16x32_fp8_fp8((a), (b), (c), 0, 0, 0)

__device__ __forceinline__ f32x4 zero4() { return (f32x4){0.f, 0.f, 0.f, 0.f}; }

__device__ __forceinline__ f32x4 wg16(const us* ap, const us* bp, int nk, f32x4 acc) {
#pragma unroll 4
    for (int k = 0; k < nk; k += 32)
        acc = MFMA(*(const s16x8*)(ap + k), *(const s16x8*)(bp + k), acc);
    return acc;
}

// async global -> LDS, 16B per lane; dest = wave-uniform base + lane*16
__device__ __forceinline__ void gload_lds16(const void* g, void* l) {
    __builtin_amdgcn_global_load_lds(
        (const __attribute__((address_space(1))) unsigned int*)g,
        (__attribute__((address_space(3))) unsigned int*)l, 16, 0, 0);
}

__device__ __forceinline__ void cvt4(const float* src, us* dst) {
    float4 v = *(const float4*)src;
    ushort4 o = { f2b(v.x), f2b(v.y), f2b(v.z), f2b(v.w) };
    *(ushort4*)dst = o;
}

// ---------------- mega prep: all conversions + weight packing + zero fills -----
__global__ __launch_bounds__(256) void k_prep(
    const float* __restrict__ ctx, us* __restrict__ ctxbf,
    const float* __restrict__ o2pW, uc* __restrict__ o2p8,
    const float* __restrict__ Wih, const float* __restrict__ Whh, us* __restrict__ Wg,
    const float* __restrict__ h2oW, us* __restrict__ h2obf,
    const float* __restrict__ octxW, us* __restrict__ octxbf,
    const float* __restrict__ att_c2c, us* __restrict__ c2cT,
    const float* __restrict__ att_h2c, us* __restrict__ attbf,
    const int* __restrict__ y, const float* __restrict__ embW, us* __restrict__ xc,
    float* __restrict__ hf32, us* __restrict__ ht_all,
    us* __restrict__ obf_all, uc* __restrict__ obf8, float* __restrict__ out) {
    __shared__ float tile[32][33];
    int bid = blockIdx.x, tid = threadIdx.x;
    const int4 z4 = {0, 0, 0, 0};

    if (bid < 1024) {                       // ctx -> bf16
        for (long i = ((long)bid * 256 + tid) * 4; i < 12845056L; i += 1048576L)
            cvt4(ctx + i, ctxbf + i);
    } else if (bid < 1792) {                // o2pW -> fp8
        for (long i = ((long)(bid - 1024) * 256 + tid) * 8; i < 16384000L;
             i += 1572864L) {
            float4 v0 = *(const float4*)(o2pW + i);
            float4 v1 = *(const float4*)(o2pW + i + 4);
            int lo = __builtin_amdgcn_cvt_pk_fp8_f32(v0.x, v0.y, 0, false);
            lo = __builtin_amdgcn_cvt_pk_fp8_f32(v0.z, v0.w, lo, true);
            int hi = __builtin_amdgcn_cvt_pk_fp8_f32(v1.x, v1.y, 0, false);
            hi = __builtin_amdgcn_cvt_pk_fp8_f32(v1.z, v1.w, hi, true);
            int2 o = { lo, hi };
            *(int2*)(o2p8 + i) = o;
        }
    } else if (bid < 2304) {                // packed gate weights (vectorized)
        for (int n = bid - 1792; n < 4096; n += 512) {
            int cl = n >> 10;
            if (cl < 2) {
                us* wb = Wg + (long)n * 2560;
                const float* wi = Wih + (long)n * 1536;
                const float* wh = Whh + (long)n * 1024;
                for (int k4 = tid; k4 < 384; k4 += 256) cvt4(wi + k4 * 4, wb + k4 * 4);
                if (tid < 256)
                    cvt4(wh + tid * 4, wb + 1536 + tid * 4);
            } else if (cl == 2) {
                us* wb = Wg + 5242880L + (long)(n - 2048) * 1536;
                const float* wi = Wih + (long)n * 1536;
                for (int k4 = tid; k4 < 384; k4 += 256) cvt4(wi + k4 * 4, wb + k4 * 4);
            } else {
                us* wb = Wg + 6815744L + (long)(n - 3072) * 1024;
                const float* wh = Whh + (long)(n - 1024) * 1024;
                cvt4(wh + tid * 4, wb + tid * 4);
            }
        }
    } else if (bid < 2368) {                // h2oW -> bf16
        for (long i = ((long)(bid - 2304) * 256 + tid) * 4; i < 524288L; i += 65536L)
            cvt4(h2oW + i, h2obf + i);
    } else if (bid < 2432) {                // octxW -> bf16
        for (long i = ((long)(bid - 2368) * 256 + tid) * 4; i < 524288L; i += 65536L)
            cvt4(octxW + i, octxbf + i);
    } else if (bid < 2560) {                // embedding gather -> xc slot0
        for (int r = bid - 2432; r < 1216; r += 128) {
            int row = y[r];
            const float* src = embW + (long)row * 512;
            us* dst = xc + (long)r * 2560;
            for (int e = tid; e < 512; e += 256) dst[e] = f2b(src[e]);
        }
    } else if (bid < 3584) {                // transpose+cvt att_c2c -> c2cT
        int g = bid - 2560;
        int bx = (g & 31) * 32, by = (g >> 5) * 32;
        int x = tid & 31, y0 = tid >> 5;
        for (int yy = y0; yy < 32; yy += 8) tile[yy][x] = att_c2c[(by + yy) * 1024 + bx + x];
        __syncthreads();
        for (int yy = y0; yy < 32; yy += 8) c2cT[(bx + yy) * 1024 + by + x] = f2b(tile[x][yy]);
    } else if (bid < 4608) {                // transpose+cvt att_h2c -> attbf
        int g = bid - 3584;
        int bx = (g & 31) * 32, by = (g >> 5) * 32;
        int x = tid & 31, y0 = tid >> 5;
        for (int yy = y0; yy < 32; yy += 8) tile[yy][x] = att_h2c[(by + yy) * 1024 + bx + x];
        __syncthreads();
        for (int yy = y0; yy < 32; yy += 8) attbf[(bx + yy) * 1024 + by + x] = f2b(tile[x][yy]);
    } else {                                // zero fills
        int zb = bid - 4608;
        if (zb < 32) {                      // hf32 (256 KiB)
            int4* p = (int4*)hf32;
            int i = zb * 256 + tid;
            p[i] = z4; p[i + 8192] = z4;
        } else if (zb < 40) {               // ht_all h0 rows (128 KiB)
            int4* p = (int4*)ht_all;
            int i = (zb - 32) * 256 + tid;
#pragma unroll
            for (int k = 0; k < 4; ++k) p[i + k * 2048] = z4;
        } else if (zb < 56) {               // xc t=0 h-slot (64 chunks x 1024 us)
            int cbase = (zb - 40) * 4;
#pragma unroll
            for (int c = 0; c < 4; ++c) {
                ushort4* p = (ushort4*)(xc + (long)(cbase + c) * 2560 + 1536);
                ushort4 o = {0, 0, 0, 0};
                p[tid] = o;
            }
        } else if (zb < 64) {               // obf_all pad rows
            int4* p = (int4*)(obf_all + 1216L * 512);
            int i = (zb - 56) * 256 + tid;
            p[i] = z4; p[i + 2048] = z4;
        } else if (zb < 68) {               // obf8 pad rows
            int4* p = (int4*)(obf8 + 1216L * 512);
            int i = (zb - 64) * 256 + tid;
            p[i] = z4; p[i + 1024] = z4;
        } else if (zb < 92) {               // o2p8 weight pad rows (384 KiB)
            int4* p = (int4*)(o2p8 + 16384000L);
            int i = (zb - 68) * 256 + tid;
#pragma unroll
            for (int k = 0; k < 4; ++k) p[i + k * 6144] = z4;
        } else {                            // d_out
            if (tid == 0) out[0] = 0.f;
        }
    }
}

// ---------------- ctx_proj GEMM (m97 structure): 128x128 tile, BK=64 ----------
__global__ __launch_bounds__(256) void k_gemm(const us* __restrict__ A,
                                              const us* __restrict__ Bt,
                                              us* __restrict__ Cb) {
    __shared__ us As[8192], Bs[8192];   // 128 rows x 64 elems each
    int tid = threadIdx.x, lane = tid & 63, w = tid >> 6;
    int mr = lane & 15, kb = lane >> 4;
    int bm = blockIdx.x % 98, bn = blockIdx.x / 98;
    long m0 = (long)bm * 128;
    int n0 = bn * 128;
    int wr = w >> 1, wc = w & 1;
    int srow = w * 32 + (lane >> 3);
    int ib = (lane & 7) * 16;

    f32x4 acc[4][4];
#pragma unroll
    for (int i = 0; i < 4; i++)
#pragma unroll
        for (int j = 0; j < 4; j++) acc[i][j] = zero4();

    for (int kt = 0; kt < 16; ++kt) {
        int k0 = kt * 64;
        __syncthreads();
#pragma unroll
        for (int c = 0; c < 4; ++c) {
            int r = srow + c * 8;
            int sw = (ib ^ ((r & 7) << 4)) >> 1;   // element offset within row
            gload_lds16(A + (m0 + r) * 1024 + k0 + sw, &As[w * 2048 + c * 512]);
            gload_lds16(Bt + (long)(n0 + r) * 1024 + k0 + sw, &Bs[w * 2048 + c * 512]);
        }
        __syncthreads();
#pragma unroll
        for (int ks = 0; ks < 2; ++ks) {
            s16x8 af[4], bf[4];
#pragma unroll
            for (int mt = 0; mt < 4; ++mt) {
                int r = wr * 64 + mt * 16 + mr;
                af[mt] = *(const s16x8*)&As[(r * 128 + ((ks * 64 + kb * 16) ^ ((r & 7) << 4))) >> 1];
            }
#pragma unroll
            for (int nt = 0; nt < 4; ++nt) {
                int r = wc * 64 + nt * 16 + mr;
                bf[nt] = *(const s16x8*)&Bs[(r * 128 + ((ks * 64 + kb * 16) ^ ((r & 7) << 4))) >> 1];
            }
#pragma unroll
            for (int mt = 0; mt < 4; ++mt)
#pragma unroll
                for (int nt = 0; nt < 4; ++nt)
                    acc[mt][nt] = MFMA(af[mt], bf[nt], acc[mt][nt]);
        }
    }
#pragma unroll
    for (int mt = 0; mt < 4; ++mt)
#pragma unroll
        for (int nt = 0; nt < 4; ++nt)
#pragma unroll
            for (int j = 0; j < 4; ++j)
                Cb[(m0 + wr * 64 + mt * 16 + kb * 4 + j) * 1024 +
                   n0 + wc * 64 + nt * 16 + mr] = f2b(acc[mt][nt][j]);
}

// ---------------- hproj parts: hpp[kc][b][n] = (h_t @ attT)_Khalf ----------------
__global__ __launch_bounds__(256) void k_hproj(const us* __restrict__ hcur,
                                               const us* __restrict__ attbf,
                                               float* __restrict__ hpp) {
    int tid = threadIdx.x, lane = tid & 63, w = tid >> 6;
    int vn0 = (blockIdx.x >> 1) * 16, kc = blockIdx.x & 1;
    int m0 = w * 16, mr = lane & 15, kb = lane >> 4;
    const us* ap = hcur + (long)(m0 + mr) * 1024 + kc * 512 + kb * 8;
    const us* bp = attbf + (long)(vn0 + mr) * 1024 + kc * 512 + kb * 8;
    f32x4 acc = wg16(ap, bp, 512, zero4());
#pragma unroll
    for (int j = 0; j < 4; ++j)
        hpp[(long)kc * 65536 + (long)(m0 + kb * 4 + j) * 1024 + vn0 + mr] = acc[j];
}

// ---------------- scores: 256 blocks (b x s-quarter), hp staged once ----------
__global__ __launch_bounds__(1024) void k_scores(const us* __restrict__ cpb,
                                                 const float* __restrict__ hpp,
                                                 const float* __restrict__ mlp,
                                                 float* __restrict__ scores) {
    __shared__ float hp[1024];
    __shared__ float ml[1024];
    int tid = threadIdx.x;
    int b = blockIdx.x >> 2, sq = blockIdx.x & 3;
    hp[tid] = hpp[(long)b * 1024 + tid] + hpp[65536 + (long)b * 1024 + tid];
    ml[tid] = mlp[tid];
    __syncthreads();
    int wv = tid >> 6, lane = tid & 63;
    int s0 = sq * 49;
    for (int s = s0 + wv; s < s0 + 49; s += 16) {
        const us* cp = cpb + (long)(s * 64 + b) * 1024 + lane * 16;
        s16x8 c0 = *(const s16x8*)cp;
        s16x8 c1 = *(const s16x8*)(cp + 8);
        int e0 = lane * 16;
        float acc = 0.f;
#pragma unroll
        for (int j = 0; j < 8; ++j)
            acc += fast_tanh(b2f((us)c0[j]) + hp[e0 + j]) * ml[e0 + j];
#pragma unroll
        for (int j = 0; j < 8; ++j)
            acc += fast_tanh(b2f((us)c1[j]) + hp[e0 + 8 + j]) * ml[e0 + 8 + j];
#pragma unroll
        for (int off = 32; off; off >>= 1) acc += __shfl_xor(acc, off, 64);
        if (lane == 0) scores[b * 196 + s] = acc;
    }
}

// ---------------- softmax + z -> xc z-slot; 512 thr, s-split halves ----------
__global__ __launch_bounds__(512) void k_z(const float* __restrict__ scores,
                                           const us* __restrict__ ctxbf,
                                           us* __restrict__ xc, int t) {
    __shared__ float red[512];
    __shared__ float als[196];
    __shared__ float zp[256];
    int tid = threadIdx.x, b = blockIdx.x >> 2, ch = blockIdx.x & 3;
    const float* sc = scores + b * 196;
    float lm = (tid < 196) ? sc[tid] : -1e30f;
    red[tid] = lm; __syncthreads();
    for (int st = 256; st; st >>= 1) { if (tid < st) red[tid] = fmaxf(red[tid], red[tid + st]); __syncthreads(); }
    float m = red[0]; __syncthreads();
    float ls = (tid < 196) ? __expf(sc[tid] - m) : 0.f;
    red[tid] = ls; __syncthreads();
    for (int st = 256; st; st >>= 1) { if (tid < st) red[tid] += red[tid + st]; __syncthreads(); }
    float inv = 1.f / red[0];
    if (tid < 196) als[tid] = ls * inv;
    __syncthreads();
    int c = ch * 256 + (tid & 255);
    int sh = tid >> 8;
    const us* cp = ctxbf + (long)b * 1024 + c;
    float a0 = 0.f;
    int sb = sh * 98;
#pragma unroll 4
    for (int s = sb; s < sb + 98; s += 2) {
        a0 += als[s] * b2f(cp[(long)s * 65536]) +
              als[s + 1] * b2f(cp[(long)(s + 1) * 65536]);
    }
    if (sh) zp[tid & 255] = a0;
    __syncthreads();
    if (!sh) {
        a0 += zp[tid & 255];
        xc[(long)(t * 64 + b) * 2560 + 512 + c] = f2b(a0);
    }
}

// ---------------- fused GRU: all 4 gates + update; XCD-co-located j-tiles -----
__global__ __launch_bounds__(512) void k_gruh2(us* __restrict__ xc,
                                               const us* __restrict__ Wg,
                                               const float* __restrict__ bih,
                                               const float* __restrict__ bhh,
                                               float* __restrict__ hf32,
                                               us* __restrict__ ht_all, int t) {
    __shared__ float lg[2048];   // [g*2+kh][m16][j16]
    int tid = threadIdx.x, lane = tid & 63, w = tid >> 6;
    int mr = lane & 15, kb = lane >> 4;
    int g = w >> 1, kh = w & 1;
    // XCD co-location: the 4 m-subtiles of a j-tile land on one XCD (bid&7)
    int xcd = blockIdx.x & 7, idx = blockIdx.x >> 3;
    int jt = xcd * 8 + (idx >> 2), mq = idx & 3;
    int m0 = mq * 16, j0 = jt * 16;
    const us* xr = xc + (long)t * 163840 + (long)(m0 + mr) * 2560;

    f32x4 acc = zero4();
    if (g == 0) {
        acc = wg16(xr + kh * 1280 + kb * 8,
                   Wg + (long)(j0 + mr) * 2560 + kh * 1280 + kb * 8, 1280, acc);
    } else if (g == 1) {
        acc = wg16(xr + kh * 1280 + kb * 8,
                   Wg + (long)(1024 + j0 + mr) * 2560 + kh * 1280 + kb * 8, 1280, acc);
    } else if (g == 2) {
        acc = wg16(xr + kh * 768 + kb * 8,
                   Wg + 5242880L + (long)(j0 + mr) * 1536 + kh * 768 + kb * 8, 768, acc);
    } else {
        acc = wg16(xr + 1536 + kh * 512 + kb * 8,
                   Wg + 6815744L + (long)(j0 + mr) * 1024 + kh * 512 + kb * 8, 512, acc);
    }
#pragma unroll
    for (int j = 0; j < 4; ++j)
        lg[(g * 2 + kh) * 256 + (kb * 4 + j) * 16 + mr] = acc[j];
    __syncthreads();

    if (tid < 256) {
        int ml = tid >> 4, jj = tid & 15;
        int b = m0 + ml, j = j0 + jj;
        float gr = lg[0 * 256 + ml * 16 + jj] + lg[1 * 256 + ml * 16 + jj];
        float gz = lg[2 * 256 + ml * 16 + jj] + lg[3 * 256 + ml * 16 + jj];
        float gi = lg[4 * 256 + ml * 16 + jj] + lg[5 * 256 + ml * 16 + jj];
        float gh = lg[6 * 256 + ml * 16 + jj] + lg[7 * 256 + ml * 16 + jj];
        float r  = sigmoidf_(gr + bih[j] + bhh[j]);
        float zz = sigmoidf_(gz + bih[1024 + j] + bhh[1024 + j]);
        float n  = fast_tanh(gi + bih[2048 + j] + r * (gh + bhh[2048 + j]));
        float h = (1.f - zz) * n + zz * hf32[b * 1024 + j];
        hf32[b * 1024 + j] = h;
        us hb = f2b(h);
        ht_all[(long)((t + 1) * 64 + b) * 1024 + j] = hb;
        if (t < TS_ - 1) xc[(long)((t + 1) * 64 + b) * 2560 + 1536 + j] = hb;
    }
}

// ---------------- batched output head: 152 blocks (19 m x 8 n of 64) ----------
__global__ __launch_bounds__(256) void k_outb(const us* __restrict__ ht_all,
                                              const us* __restrict__ xc,
                                              const us* __restrict__ h2obf,
                                              const float* __restrict__ h2ob,
                                              const us* __restrict__ octxbf,
                                              const float* __restrict__ octxb,
                                              us* __restrict__ obf_all,
                                              uc* __restrict__ obf8) {
    int tid = threadIdx.x, lane = tid & 63, w = tid >> 6;
    int mr = lane & 15, kb = lane >> 4;
    int m0 = blockIdx.x * 64;
    int n0 = blockIdx.y * 64;
    int e = n0 + w * 16 + mr;
    const us* bb1 = h2obf + (long)e * 1024 + kb * 8;
    const us* bb2 = octxbf + (long)e * 1024 + kb * 8;
    const us* ab1 = ht_all + (long)(64 + m0 + mr) * 1024 + kb * 8;
    const us* ab2 = xc + (long)(m0 + mr) * 2560 + 512 + kb * 8;

    f32x4 a1[4], a2[4];
#pragma unroll
    for (int i = 0; i < 4; i++) { a1[i] = zero4(); a2[i] = zero4(); }

#pragma unroll 2
    for (int k0 = 0; k0 < 1024; k0 += 32) {
        s16x8 b1 = *(const s16x8*)(bb1 + k0);
        s16x8 b2 = *(const s16x8*)(bb2 + k0);
#pragma unroll
        for (int mt = 0; mt < 4; ++mt) {
            a1[mt] = MFMA(*(const s16x8*)(ab1 + mt * 16384 + k0), b1, a1[mt]);
            a2[mt] = MFMA(*(const s16x8*)(ab2 + mt * 40960 + k0), b2, a2[mt]);
        }
    }
    float b1v = h2ob[e], b2v = octxb[e];
#pragma unroll
    for (int mt = 0; mt < 4; ++mt)
#pragma unroll
        for (int j = 0; j < 4; ++j) {
            long row = m0 + mt * 16 + kb * 4 + j;
            float ye = b2f(xc[row * 2560 + e]);
            float val = fast_tanh(fast_tanh(a1[mt][j] + b1v) + ye + a2[mt][j] + b2v);
            obf_all[(row << 9) + e] = f2b(val);
            obf8[(row << 9) + e] = f2e4m3(val);
        }
}

// ---------------- vocab GEMM (fp8, dbuf LDS, 1 barrier/K-tile) + partial LSE ---
__global__ __launch_bounds__(256) void k_vocab8(const uc* __restrict__ obf8,
                                                const uc* __restrict__ o2p8,
                                                const float* __restrict__ o2pb,
                                                float* __restrict__ pm,
                                                float* __restrict__ ps) {
    __shared__ uc As[2][8192], Bs[2][8192];   // dbuf: 128 rows x 64 B each
    int tid = threadIdx.x, lane = tid & 63, w = tid >> 6;
    int mr = lane & 15, kb = lane >> 4;
    int xq = blockIdx.x & 7, idx = blockIdx.x >> 3;
    int nb = xq * 32 + idx / 10, mb = idx % 10;
    int m0 = mb * 128, n0 = nb * 128;
    int wr = w >> 1, wc = w & 1;
    int srow = w * 32 + (lane >> 2);
    int ib = (lane & 3) * 16;

    f32x4 acc[4][4];
#pragma unroll
    for (int i = 0; i < 4; i++)
#pragma unroll
        for (int j = 0; j < 4; j++) acc[i][j] = zero4();

    // prologue: stage kt=0 into buf 0
#pragma unroll
    for (int c = 0; c < 2; ++c) {
        int r = srow + c * 16;
        int sw = ib ^ ((r & 6) << 3);
        gload_lds16(obf8 + (long)(m0 + r) * 512 + sw, &As[0][w * 2048 + c * 1024]);
        gload_lds16(o2p8 + (long)(n0 + r) * 512 + sw, &Bs[0][w * 2048 + c * 1024]);
    }
    __syncthreads();

    int buf = 0;
    for (int kt = 0; kt < 8; ++kt) {
        if (kt < 7) {
            int k1 = (kt + 1) * 64;
#pragma unroll
            for (int c = 0; c < 2; ++c) {
                int r = srow + c * 16;
                int sw = ib ^ ((r & 6) << 3);
                gload_lds16(obf8 + (long)(m0 + r) * 512 + k1 + sw,
                            &As[buf ^ 1][w * 2048 + c * 1024]);
                gload_lds16(o2p8 + (long)(n0 + r) * 512 + k1 + sw,
                            &Bs[buf ^ 1][w * 2048 + c * 1024]);
            }
        }
#pragma unroll
        for (int ks = 0; ks < 2; ++ks) {
            long af[4], bf[4];
#pragma unroll
            for (int mt = 0; mt < 4; ++mt) {
                int r = wr * 64 + mt * 16 + mr;
                af[mt] = *(const long*)&As[buf][r * 64 + ((ks * 32 + kb * 8) ^ ((r & 6) << 3))];
            }
#pragma unroll
            for (int nt = 0; nt < 4; ++nt) {
                int r = wc * 64 + nt * 16 + mr;
                bf[nt] = *(const long*)&Bs[buf][r * 64 + ((ks * 32 + kb * 8) ^ ((r & 6) << 3))];
            }
#pragma unroll
            for (int mt = 0; mt < 4; ++mt)
#pragma unroll
                for (int nt = 0; nt < 4; ++nt)
                    acc[mt][nt] = MFMA8(af[mt], bf[nt], acc[mt][nt]);
        }
        __syncthreads();   // drains vmcnt -> buf^1 staged; LDS reuse safe
        buf ^= 1;
    }

    int n0w = n0 + wc * 64;
    float bv[4];
#pragma unroll
    for (int nt = 0; nt < 4; ++nt) {
        int vn = n0w + nt * 16 + mr;
        bv[nt] = (vn < 32000) ? o2pb[vn] : -1e30f;
    }
#pragma unroll
    for (int mt = 0; mt < 4; ++mt)
#pragma unroll
        for (int j = 0; j < 4; ++j) {
            float x0 = acc[mt][0][j] + bv[0];
            float x1 = acc[mt][1][j] + bv[1];
            float x2 = acc[mt][2][j] + bv[2];
            float x3 = acc[mt][3][j] + bv[3];
            float m = fmaxf(fmaxf(x0, x1), fmaxf(x2, x3));
            float s = __expf(x0 - m) + __expf(x1 - m) + __expf(x2 - m) + __expf(x3 - m);
#pragma unroll
            for (int off = 1; off <= 8; off <<= 1) {
                float mo = __shfl_xor(m, off, 64), so = __shfl_xor(s, off, 64);
                float nm = fmaxf(m, mo);
                s = s * __expf(m - nm) + so * __expf(mo - nm);
                m = nm;
            }
            if (mr == 0) {
                int row = m0 + wr * 64 + mt * 16 + kb * 4 + j;
                pm[(long)(nb * 2 + wc) * 1280 + row] = m;
                ps[(long)(nb * 2 + wc) * 1280 + row] = s;
            }
        }
}

// ---------------- final LSE reduce + NLL accumulate ----------------
__global__ __launch_bounds__(64) void k_lseb(const float* __restrict__ pm,
                                             const float* __restrict__ ps,
                                             const us* __restrict__ obf_all,
                                             const float* __restrict__ o2pW,
                                             const float* __restrict__ o2pb,
                                             const int* __restrict__ y,
                                             float* __restrict__ out) {
    int r = blockIdx.x, lane = threadIdx.x;
    int t = r >> 6, b = r & 63;
    int tgt = y[(t + 1) * 64 + b];
    float m = -1e30f, s = 0.f;
    for (int p = lane; p < 512; p += 64) {
        float mi = pm[(long)p * 1280 + r], si = ps[(long)p * 1280 + r];
        float nm = fmaxf(m, mi);
        s = s * __expf(m - nm) + si * __expf(mi - nm);
        m = nm;
    }
#pragma unroll
    for (int off = 32; off; off >>= 1) {
        float mo = __shfl_xor(m, off, 64), so = __shfl_xor(s, off, 64);
        float nm = fmaxf(m, mo);
        s = s * __expf(m - nm) + so * __expf(mo - nm);
        m = nm;
    }
    float d = 0.f;
    const float* wr = o2pW + (long)tgt * 512;
#pragma unroll
    for (int k = 0; k < 8; ++k)
        d += b2f(obf_all[(long)r * 512 + lane + k * 64]) * wr[lane + k * 64];
#pragma unroll
    for (int off = 32; off; off >>= 1) d += __shfl_xor(d, off, 64);
    if (lane == 0 && tgt != 0)
        atomicAdd(out, (m + __logf(s)) - (d + o2pb[tgt]));
}

extern "C" void kernel_launch(void* const* d_in, const int* in_sizes, int n_in,
                              void* d_out, int out_size, void* d_ws, size_t ws_size,
                              hipStream_t stream) {
    const float* ctx     = (const float*)d_in[0];
    const int*   y       = (const int*)d_in[1];
    const float* embW    = (const float*)d_in[2];
    const float* att_c2c = (const float*)d_in[3];
    const float* att_h2c = (const float*)d_in[4];
    const float* mlp     = (const float*)d_in[5];
    const float* Wih     = (const float*)d_in[6];
    const float* bih     = (const float*)d_in[7];
    const float* Whh     = (const float*)d_in[8];
    const float* bhh     = (const float*)d_in[9];
    const float* h2oW    = (const float*)d_in[10];
    const float* h2ob    = (const float*)d_in[11];
    const float* octxW   = (const float*)d_in[12];
    const float* octxb   = (const float*)d_in[13];
    const float* o2pW    = (const float*)d_in[14];
    const float* o2pb    = (const float*)d_in[15];
    float* out = (float*)d_out;

    char* base = (char*)d_ws;
    us* ctxbf   = (us*)base; base += 25690112L;   // [s][b][c] bf16 (= GEMM A)
    us* cpbf    = (us*)base; base += 25690112L;   // [12544][1024]; pm/ps alias after loop
    us* c2cT    = (us*)base; base += 2097152L;
    us* attbf   = (us*)base; base += 2097152L;
    us* Wg      = (us*)base; base += 15728640L;
    us* h2obf   = (us*)base; base += 1048576L;
    us* octxbf  = (us*)base; base += 1048576L;
    uc* o2p8    = (uc*)base; base += 16777216L;   // [32768][512] fp8, rows 32000+ zero
    us* xc      = (us*)base; base += 6225920L;    // [19][64][2560]
    us* ht_all  = (us*)base; base += 2621440L;    // [20*64][1024], rows 0..63 = h0 = 0
    us* obf_all = (us*)base; base += 1310720L;    // [1280][512] bf16, rows 1216+ pad
    uc* obf8    = (uc*)base; base += 655360L;     // [1280][512] fp8
    float* hf32   = (float*)base; base += 262144L;  // [64][1024]
    float* hpp    = (float*)base; base += 524288L;  // [2][64][1024]
    float* scb    = (float*)base; base += 50176L;   // [64][196]
    float* pm   = (float*)cpbf;                   // [512][1280] aliases cpbf (dead by then)
    float* ps   = pm + 655360L;

    // one mega prep kernel: all conversions + packing + zero fills + d_out=0
    k_prep<<<4701, 256, 0, stream>>>(ctx, ctxbf, o2pW, o2p8, Wih, Whh, Wg,
                                     h2oW, h2obf, octxW, octxbf,
                                     att_c2c, c2cT, att_h2c, attbf,
                                     y, embW, xc, hf32, ht_all, obf_all, obf8, out);
    k_gemm<<<784, 256, 0, stream>>>(ctxbf, c2cT, cpbf);

    // sequential recurrence: 4 kernels per step
    for (int t = 0; t < TS_; t++) {
        k_hproj<<<128, 256, 0, stream>>>(ht_all + (long)t * 65536, attbf, hpp);
        k_scores<<<256, 1024, 0, stream>>>(cpbf, hpp, mlp, scb);
        k_z<<<256, 512, 0, stream>>>(scb, ctxbf, xc, t);
        k_gruh2<<<256, 512, 0, stream>>>(xc, Wg, bih, bhh, hf32, ht_all, t);
    }

    // deferred output head, batched over all steps
    k_outb<<<dim3(19, 8), 256, 0, stream>>>(ht_all, xc, h2obf, h2ob, octxbf, octxb,
                                            obf_all, obf8);
    k_vocab8<<<2560, 256, 0, stream>>>(obf8, o2p8, o2pb, pm, ps);
    k_lseb<<<1216, 64, 0, stream>>>(pm, ps, obf_all, o2pW, o2pb, y, out);
}